// Round 8
// baseline (507.522 us; speedup 1.0000x reference)
//
#include <hip/hip_runtime.h>
#include <hip/hip_bf16.h>

// Problem constants: B=2, T=2048, D=1024, H=16, G=4, K=64, F=4096
#define EPSF 1e-6f
constexpr int Bsz  = 2;
constexpr int Tseq = 2048;
constexpr int Dmod = 1024;
constexpr int Hh   = 16;
constexpr int Gg   = 4;
constexpr int Ff   = 4096;
constexpr int Mrows = Bsz * Tseq;          // 4096 tokens

typedef __attribute__((ext_vector_type(8))) short bf16x8;   // 8 bf16 (4 VGPRs)
typedef __attribute__((ext_vector_type(4))) float f32x4;
typedef unsigned short u16;

// RNE fp32 -> bf16 (bit pattern as u16)
__device__ inline u16 f2bf(float x) {
    union { float f; unsigned u; } v; v.f = x;
    unsigned r = v.u + 0x7fff + ((v.u >> 16) & 1);
    return (u16)(r >> 16);
}
__device__ inline float bf2f(u16 h) {
    union { unsigned u; float f; } v; v.u = ((unsigned)h) << 16; return v.f;
}

// Async global->LDS DMA, 16 B per lane (wave-uniform base + lane*16).
__device__ __forceinline__ void async_copy16(const u16* g, u16* l) {
    __builtin_amdgcn_global_load_lds(
        (const __attribute__((address_space(1))) void*)g,
        (__attribute__((address_space(3))) void*)l, 16, 0, 0);
}

// Bank-swizzle: LDS tiles [row][32] bf16 (64 B rows). Logical k-chunk q of row
// R stored at chunk q ^ ((R>>1)&3); staging fetches global chunk
// (lane&3)^((row>>1)&3) into linear dest lane*16; reads XOR the same term.
// Conflict-free ONLY for the 16x16 read geometry — verified r7/r10 (=0).
// The 32x32 read geometry conflicts under ANY chunk-XOR (r11/r12, 1.05e7).
//
// GEMM tile-size lesson (r15): BN=64 regressed o/down-proj ~+11us vs BN=128 —
// halved MFMA/K-step at constant barrier overhead + doubled A re-reads beats
// the co-residency gain. BN=128 final. gateup stays at r10-exact (131us/45%;
// r11/r12 32x32 and r14 4x2-retile both refuted).
// Attn lesson (r16): halving K/V traffic via window pairing was NEUTRAL —
// attn is critical-path-bound, not traffic-bound. r17 balances the per-CU
// iteration load instead (see attn kernel comment).

// ---------------------------------------------------------------------------
// ALL weight prep in ONE launch + FUSED rmsnorm(ln1) blocks appended (r17:
// rmsnorm1 is independent of weight prep; folding it into this grid fills the
// dispatch tail instead of serializing behind it). Blocks 0..14847 = wprep,
// 14848..18943 = rmsnorm rows. Numerics of both parts unchanged.
// ---------------------------------------------------------------------------
__global__ __launch_bounds__(256) void wprep_all_kernel(
    const float* __restrict__ q_w, const float* __restrict__ k_w,
    const float* __restrict__ v_w, const float* __restrict__ o_w,
    const float* __restrict__ gate_w, const float* __restrict__ up_w,
    const float* __restrict__ down_w,
    const float* __restrict__ hidden, const float* __restrict__ ln1,
    u16* __restrict__ QKVT, u16* __restrict__ OTh, u16* __restrict__ OTl,
    u16* __restrict__ GTh, u16* __restrict__ UTh, u16* __restrict__ DTh,
    u16* __restrict__ Xh)
{
    const int bx = blockIdx.x;

    if (bx >= 14848) {
        // ---- fused rmsnorm(hidden, ln1) -> Xh, one block per token ----
        const int row = bx - 14848;
        const int tid = threadIdx.x;
        const float4 v = reinterpret_cast<const float4*>(hidden + (size_t)row * Dmod)[tid];
        float ss = v.x * v.x + v.y * v.y + v.z * v.z + v.w * v.w;
        #pragma unroll
        for (int off = 32; off; off >>= 1) ss += __shfl_xor(ss, off, 64);
        __shared__ float part[4];
        if ((tid & 63) == 0) part[tid >> 6] = ss;
        __syncthreads();
        const float tot = part[0] + part[1] + part[2] + part[3];
        const float rstd = rsqrtf(tot * (1.0f / Dmod) + EPSF);
        const float4 sc = reinterpret_cast<const float4*>(ln1)[tid];
        ushort4 h;
        h.x = f2bf(v.x * rstd * sc.x); h.y = f2bf(v.y * rstd * sc.y);
        h.z = f2bf(v.z * rstd * sc.z); h.w = f2bf(v.w * rstd * sc.w);
        *reinterpret_cast<ushort4*>(&Xh[(size_t)row * Dmod + tid * 4]) = h;
        return;
    }

    const float* W; u16* Th; u16* Tl = nullptr;
    int N, Kd, ntile, ktile, drow;
    if (bx < 1024) {
        W = q_w; N = 1024; Kd = 1024; ntile = bx & 31; ktile = bx >> 5;
        Th = QKVT; drow = ntile * 32;
    } else if (bx < 1280) {
        const int i = bx - 1024;
        W = k_w; N = 256; Kd = 1024; ntile = i & 7; ktile = i >> 3;
        Th = QKVT; drow = 1024 + ntile * 32;
    } else if (bx < 1536) {
        const int i = bx - 1280;
        W = v_w; N = 256; Kd = 1024; ntile = i & 7; ktile = i >> 3;
        Th = QKVT; drow = 1280 + ntile * 32;
    } else if (bx < 2560) {
        const int i = bx - 1536;
        W = o_w; N = 1024; Kd = 1024; ntile = i & 31; ktile = i >> 5;
        Th = OTh; Tl = OTl; drow = ntile * 32;
    } else if (bx < 6656) {
        const int i = bx - 2560;
        W = gate_w; N = 4096; Kd = 1024; ntile = i & 127; ktile = i >> 7;
        Th = GTh; drow = ntile * 32;
    } else if (bx < 10752) {
        const int i = bx - 6656;
        W = up_w; N = 4096; Kd = 1024; ntile = i & 127; ktile = i >> 7;
        Th = UTh; drow = ntile * 32;
    } else {
        const int i = bx - 10752;
        W = down_w; N = 1024; Kd = 4096; ntile = i & 31; ktile = i >> 5;
        Th = DTh; drow = ntile * 32;
    }
    const int n0 = ntile * 32, k0 = ktile * 32;

    __shared__ float tile[32][33];
    const int r = threadIdx.x >> 3, c4 = (threadIdx.x & 7) * 4;
    const float4 v = *reinterpret_cast<const float4*>(&W[(size_t)(k0 + r) * N + n0 + c4]);
    tile[r][c4 + 0] = v.x; tile[r][c4 + 1] = v.y;
    tile[r][c4 + 2] = v.z; tile[r][c4 + 3] = v.w;
    __syncthreads();
    const int nl = threadIdx.x >> 3, kq = (threadIdx.x & 7) * 4;
    float x0 = tile[kq + 0][nl], x1 = tile[kq + 1][nl];
    float x2 = tile[kq + 2][nl], x3 = tile[kq + 3][nl];
    ushort4 h;
    h.x = f2bf(x0); h.y = f2bf(x1); h.z = f2bf(x2); h.w = f2bf(x3);
    *reinterpret_cast<ushort4*>(&Th[(size_t)(drow + nl) * Kd + k0 + kq]) = h;
    if (Tl) {
        ushort4 l;
        l.x = f2bf(x0 - bf2f(h.x)); l.y = f2bf(x1 - bf2f(h.y));
        l.z = f2bf(x2 - bf2f(h.z)); l.w = f2bf(x3 - bf2f(h.w));
        *reinterpret_cast<ushort4*>(&Tl[(size_t)(drow + nl) * Kd + k0 + kq]) = l;
    }
}

// ---------------------------------------------------------------------------
// RMSNorm over D=1024 -> bf16 hi (+ optional lo). One block per token.
// (Still used standalone for ln2; ln1 instance is fused into wprep.)
// ---------------------------------------------------------------------------
template <int LO>
__global__ __launch_bounds__(256) void rmsnorm_split_kernel(
    const float* __restrict__ x, const float* __restrict__ scale,
    u16* __restrict__ oh, u16* __restrict__ ol)
{
    const int row = blockIdx.x;
    const int tid = threadIdx.x;
    const float4 v = reinterpret_cast<const float4*>(x + (size_t)row * Dmod)[tid];
    float ss = v.x * v.x + v.y * v.y + v.z * v.z + v.w * v.w;
    #pragma unroll
    for (int off = 32; off; off >>= 1) ss += __shfl_xor(ss, off, 64);
    __shared__ float part[4];
    if ((tid & 63) == 0) part[tid >> 6] = ss;
    __syncthreads();
    const float tot = part[0] + part[1] + part[2] + part[3];
    const float rstd = rsqrtf(tot * (1.0f / Dmod) + EPSF);
    const float4 sc = reinterpret_cast<const float4*>(scale)[tid];
    float o0 = v.x * rstd * sc.x, o1 = v.y * rstd * sc.y;
    float o2 = v.z * rstd * sc.z, o3 = v.w * rstd * sc.w;
    ushort4 h;
    h.x = f2bf(o0); h.y = f2bf(o1); h.z = f2bf(o2); h.w = f2bf(o3);
    *reinterpret_cast<ushort4*>(&oh[(size_t)row * Dmod + tid * 4]) = h;
    if (LO) {
        ushort4 l;
        l.x = f2bf(o0 - bf2f(h.x)); l.y = f2bf(o1 - bf2f(h.y));
        l.z = f2bf(o2 - bf2f(h.z)); l.w = f2bf(o3 - bf2f(h.w));
        *reinterpret_cast<ushort4*>(&ol[(size_t)row * Dmod + tid * 4]) = l;
    }
}

// ---------------------------------------------------------------------------
// Split-bf16 MFMA GEMM, r13 pipeline (BN kept as template param; BN=128 is
// the proven config — see tile-size lesson above).
// ---------------------------------------------------------------------------
template <int NKT, int BN, int ASPLIT, int BSPLIT, int RES>
__global__ __launch_bounds__(256, 2) void mfma_gemm_pipe(
    const u16* __restrict__ Ah, const u16* __restrict__ Al,
    const u16* __restrict__ Bh, const u16* __restrict__ Bl,
    const float* __restrict__ res, float* __restrict__ C,
    int M, int N)
{
    constexpr int Kd = NKT * 32;
    constexpr int NT = (BN / 2) / 16;                 // n-frags per wave
    constexpr int NI = 2 + 2 * ASPLIT + (BN / 64) + (BN / 64) * BSPLIT;
    static_assert((NKT - 2) % 3 == 0, "main loop unroll-3");

    __shared__ u16 AsH[3][128 * 32];                  // 24 KB
    __shared__ u16 BsH[3][BN * 32];                   // 24/12 KB
    __shared__ u16 AsL[ASPLIT ? 3 : 1][128 * 32];     // 24/8 KB
    __shared__ u16 BsL[BSPLIT ? 3 : 1][BN * 32];      // 24|12 / 8|4 KB

    const int tid = threadIdx.x;
    const int lane = tid & 63, wave = tid >> 6;
    const int wm = (wave >> 1) * 64, wn = (wave & 1) * (BN / 2);
    const int m0 = blockIdx.y * 128, n0 = blockIdx.x * BN;
    const int fm = lane & 15, quad = lane >> 4;
    const int fsw = (fm >> 1) & 3;
    const int fcol = (quad ^ fsw) * 8;

    f32x4 acc[4][NT];
    #pragma unroll
    for (int i = 0; i < 4; ++i)
        #pragma unroll
        for (int j = 0; j < NT; ++j) acc[i][j] = (f32x4){0.f, 0.f, 0.f, 0.f};

    // staging: 256 thr * 16 B = 4 KB/issue; 128x32 tile = 2 issues, 64x32 = 1
    const int srow = tid >> 2;             // 0..63
    const int schk = tid & 3;
    const int sw   = schk ^ ((srow >> 1) & 3);   // f(srow+64)==f(srow)
    const u16* aS0 = &Ah[(size_t)(m0 + srow) * Kd + sw * 8];
    const u16* aS1 = &Ah[(size_t)(m0 + srow + 64) * Kd + sw * 8];
    const u16* bS0 = &Bh[(size_t)(n0 + srow) * Kd + sw * 8];
    const u16* bS1 = (BN == 128) ? &Bh[(size_t)(n0 + srow + 64) * Kd + sw * 8] : nullptr;
    const u16* alS0 = ASPLIT ? &Al[(size_t)(m0 + srow) * Kd + sw * 8] : nullptr;
    const u16* alS1 = ASPLIT ? &Al[(size_t)(m0 + srow + 64) * Kd + sw * 8] : nullptr;
    const u16* blS0 = BSPLIT ? &Bl[(size_t)(n0 + srow) * Kd + sw * 8] : nullptr;
    const u16* blS1 = (BSPLIT && BN == 128) ? &Bl[(size_t)(n0 + srow + 64) * Kd + sw * 8] : nullptr;
    const int dst0 = srow * 32 + schk * 8;       // bytes = tid*16 (linear)
    const int dst1 = dst0 + 64 * 32;

#define PSTAGE(T, BUF) do {                                                  \
        async_copy16(aS0 + (T) * 32, &AsH[BUF][dst0]);                       \
        async_copy16(aS1 + (T) * 32, &AsH[BUF][dst1]);                       \
        if (ASPLIT) {                                                        \
            async_copy16(alS0 + (T) * 32, &AsL[BUF][dst0]);                  \
            async_copy16(alS1 + (T) * 32, &AsL[BUF][dst1]);                  \
        }                                                                    \
        async_copy16(bS0 + (T) * 32, &BsH[BUF][dst0]);                       \
        if (BN == 128) async_copy16(bS1 + (T) * 32, &BsH[BUF][dst1]);        \
        if (BSPLIT) {                                                        \
            async_copy16(blS0 + (T) * 32, &BsL[BUF][dst0]);                  \
            if (BN == 128) async_copy16(blS1 + (T) * 32, &BsL[BUF][dst1]);   \
        }                                                                    \
    } while (0)

// GATE: 1 = steady-state counted wait vmcnt(NI), 0 = drain, -1 = none.
// Counting: at the gate, outstanding = t+1's NI (older) + t+2's NI (younger);
// vmcnt(NI) completes all of t+1's (FIFO, m135).
#define PGATE(GATE) do {                                                     \
        if ((GATE) == 1) {                                                   \
            if constexpr (NI == 3)                                           \
                asm volatile("s_waitcnt vmcnt(3)" ::: "memory");             \
            else if constexpr (NI == 4)                                      \
                asm volatile("s_waitcnt vmcnt(4)" ::: "memory");             \
            else if constexpr (NI == 6)                                      \
                asm volatile("s_waitcnt vmcnt(6)" ::: "memory");             \
            else                                                             \
                asm volatile("s_waitcnt vmcnt(8)" ::: "memory");             \
        } else if ((GATE) == 0) {                                            \
            asm volatile("s_waitcnt vmcnt(0)" ::: "memory");                 \
        }                                                                    \
    } while (0)

#define PSTEP(BC, BN_, T, PF, GATE) do {                                     \
    bf16x8 ah[4], bh[NT], al[4], bl[NT];                                     \
    _Pragma("unroll")                                                        \
    for (int t = 0; t < 4; ++t) {                                            \
        const int ra = (wm + t * 16 + fm) * 32 + fcol;                       \
        ah[t] = *reinterpret_cast<const bf16x8*>(&AsH[BC][ra]);              \
        if (ASPLIT) al[t] = *reinterpret_cast<const bf16x8*>(&AsL[BC][ra]);  \
    }                                                                        \
    _Pragma("unroll")                                                        \
    for (int t = 0; t < NT; ++t) {                                           \
        const int rb = (wn + t * 16 + fm) * 32 + fcol;                       \
        bh[t] = *reinterpret_cast<const bf16x8*>(&BsH[BC][rb]);              \
        if (BSPLIT) bl[t] = *reinterpret_cast<const bf16x8*>(&BsL[BC][rb]);  \
    }                                                                        \
    if (PF) PSTAGE((T) + 2, BN_);                                            \
    __builtin_amdgcn_s_barrier();                                            \
    asm volatile("s_waitcnt lgkmcnt(0)" ::: "memory");                       \
    __builtin_amdgcn_sched_barrier(0);                                       \
    __builtin_amdgcn_s_setprio(1);                                           \
    _Pragma("unroll")                                                        \
    for (int mt = 0; mt < 4; ++mt)                                           \
        _Pragma("unroll")                                                    \
        for (int nt = 0; nt < NT; ++nt) {                                    \
            acc[mt][nt] = __builtin_amdgcn_mfma_f32_16x16x32_bf16(           \
                ah[mt], bh[nt], acc[mt][nt], 0, 0, 0);                       \
            if (BSPLIT)                                                      \
                acc[mt][nt] = __builtin_amdgcn_mfma_f32_16x16x32_bf16(       \
                    ah[mt], bl[nt], acc[mt][nt], 0, 0, 0);                   \
            if (ASPLIT)                                                      \
                acc[mt][nt] = __builtin_amdgcn_mfma_f32_16x16x32_bf16(       \
                    al[mt], bh[nt], acc[mt][nt], 0, 0, 0);                   \
        }                                                                    \
    __builtin_amdgcn_s_setprio(0);                                           \
    PGATE(GATE);                                                             \
    __builtin_amdgcn_s_barrier();                                            \
} while (0)

    // prologue: fill buffers 0 and 1 (2*NI in flight -> wait NI = buf0 done)
    PSTAGE(0, 0);
    PSTAGE(1, 1);
    PGATE(1);
    __builtin_amdgcn_s_barrier();

    #pragma unroll 1
    for (int t3 = 0; t3 < NKT - 2; t3 += 3) {
        PSTEP(0, 2, t3 + 0, true, 1);
        PSTEP(1, 0, t3 + 1, true, 1);
        PSTEP(2, 1, t3 + 2, true, 1);
    }
    // tail: t=NKT-2 (buf0, drain last loads), t=NKT-1 (buf1, nothing left)
    PSTEP(0, 2, NKT - 2, false, 0);
    PSTEP(1, 0, NKT - 1, false, -1);

#undef PSTEP
#undef PGATE
#undef PSTAGE

    const int cr = (lane >> 4) * 4, cn = lane & 15;
    #pragma unroll
    for (int mt = 0; mt < 4; ++mt)
        #pragma unroll
        for (int nt = 0; nt < NT; ++nt)
            #pragma unroll
            for (int r = 0; r < 4; ++r) {
                const int gm = m0 + wm + mt * 16 + cr + r;
                const int gn = n0 + wn + nt * 16 + cn;
                float v = acc[mt][nt][r];
                if (RES) v += res[(size_t)gm * N + gn];
                C[(size_t)gm * N + gn] = v;
            }
}

// ---------------------------------------------------------------------------
// Fused QKV GEMM + qk-norm + RoPE + bf16 split epilogue; V stored TRANSPOSED.
// r14: K-loop uses the r13-proven pipelined structure (triple buffer, counted
// vmcnt(4), setprio). Proven ~-13us in r14's bench. Epilogue unchanged.
// ---------------------------------------------------------------------------
__global__ __launch_bounds__(256, 2) void qkv_fused_kernel(
    const u16* __restrict__ Ah, const u16* __restrict__ Bh,
    const float* __restrict__ qn, const float* __restrict__ kn,
    const float* __restrict__ sinp, const float* __restrict__ cosp,
    u16* __restrict__ Qbh, u16* __restrict__ Qbl,
    u16* __restrict__ Kbh, u16* __restrict__ Kbl,
    u16* __restrict__ Vth, u16* __restrict__ Vtl)
{
    constexpr int Kd = 1024;
    constexpr int NKT = 32;
    __shared__ u16 As[3][128 * 32];    // 24 KB
    __shared__ u16 Bs[3][128 * 32];    // 24 KB -> 48 KB total

    const int tid = threadIdx.x;
    const int lane = tid & 63, wave = tid >> 6;
    const int wm = (wave >> 1) * 64, wn = (wave & 1) * 64;
    const int m0 = blockIdx.y * 128, n0 = blockIdx.x * 128;
    const int fm = lane & 15, quad = lane >> 4;
    const int fsw = (fm >> 1) & 3;
    const int fcol = ((quad ^ fsw) * 8);

    f32x4 acc[4][4];
    #pragma unroll
    for (int i = 0; i < 4; ++i)
        #pragma unroll
        for (int j = 0; j < 4; ++j) acc[i][j] = (f32x4){0.f, 0.f, 0.f, 0.f};

    const int srow = tid >> 2;             // 0..63
    const int schk = tid & 3;
    const int sw   = schk ^ ((srow >> 1) & 3);
    const u16* aS0 = &Ah[(size_t)(m0 + srow) * Kd + sw * 8];
    const u16* aS1 = &Ah[(size_t)(m0 + srow + 64) * Kd + sw * 8];
    const u16* bS0 = &Bh[(size_t)(n0 + srow) * Kd + sw * 8];
    const u16* bS1 = &Bh[(size_t)(n0 + srow + 64) * Kd + sw * 8];
    const int dst0 = srow * 32 + schk * 8;
    const int dst1 = dst0 + 64 * 32;

#define QSTAGE(T, BUF) do {                                                  \
        async_copy16(aS0 + (T) * 32, &As[BUF][dst0]);                        \
        async_copy16(aS1 + (T) * 32, &As[BUF][dst1]);                        \
        async_copy16(bS0 + (T) * 32, &Bs[BUF][dst0]);                        \
        async_copy16(bS1 + (T) * 32, &Bs[BUF][dst1]);                        \
    } while (0)

#define QSTEP(BC, BN, T, PF, GATE) do {                                      \
    bf16x8 ah[4], bh[4];                                                     \
    _Pragma("unroll")                                                        \
    for (int t = 0; t < 4; ++t) {                                            \
        ah[t] = *reinterpret_cast<const bf16x8*>(                            \
            &As[BC][(wm + t * 16 + fm) * 32 + fcol]);                        \
        bh[t] = *reinterpret_cast<const bf16x8*>(                            \
            &Bs[BC][(wn + t * 16 + fm) * 32 + fcol]);                        \
    }                                                                        \
    if (PF) QSTAGE((T) + 2, BN);                                             \
    __builtin_amdgcn_s_barrier();                                            \
    asm volatile("s_waitcnt lgkmcnt(0)" ::: "memory");                       \
    __builtin_amdgcn_sched_barrier(0);                                       \
    __builtin_amdgcn_s_setprio(1);                                           \
    _Pragma("unroll")                                                        \
    for (int mt = 0; mt < 4; ++mt)                                           \
        _Pragma("unroll")                                                    \
        for (int nt = 0; nt < 4; ++nt)                                       \
            acc[mt][nt] = __builtin_amdgcn_mfma_f32_16x16x32_bf16(           \
                ah[mt], bh[nt], acc[mt][nt], 0, 0, 0);                       \
    __builtin_amdgcn_s_setprio(0);                                           \
    if ((GATE) == 1) {                                                       \
        asm volatile("s_waitcnt vmcnt(4)" ::: "memory");                     \
    } else if ((GATE) == 0) {                                                \
        asm volatile("s_waitcnt vmcnt(0)" ::: "memory");                     \
    }                                                                        \
    __builtin_amdgcn_s_barrier();                                            \
} while (0)

    QSTAGE(0, 0);
    QSTAGE(1, 1);
    asm volatile("s_waitcnt vmcnt(4)" ::: "memory");
    __builtin_amdgcn_s_barrier();

    #pragma unroll 1
    for (int t3 = 0; t3 < NKT - 2; t3 += 3) {
        QSTEP(0, 2, t3 + 0, true, 1);
        QSTEP(1, 0, t3 + 1, true, 1);
        QSTEP(2, 1, t3 + 2, true, 1);
    }
    QSTEP(0, 2, NKT - 2, false, 0);
    QSTEP(1, 0, NKT - 1, false, -1);

#undef QSTEP
#undef QSTAGE

    const int gn0 = n0 + wn;          // wave col base, 64-aligned
    const int l15 = lane & 15;

    if (gn0 < 1280) {
        // ---- Q or K: per-head RMSNorm + RoPE + split ----
        const bool isQ = (gn0 < 1024);
        const float* nsc = isQ ? qn : kn;
        const float osc = isQ ? 0.125f : 1.0f;
        u16* __restrict__ oh = isQ ? Qbh : Kbh;
        u16* __restrict__ ol = isQ ? Qbl : Kbl;
        const int rowstride = isQ ? 1024 : 256;
        const int colbase = isQ ? gn0 : gn0 - 1024;
        float sc[4];
        #pragma unroll
        for (int nt = 0; nt < 4; ++nt) sc[nt] = nsc[nt * 16 + l15];

        #pragma unroll
        for (int mt = 0; mt < 4; ++mt)
            #pragma unroll
            for (int r = 0; r < 4; ++r) {
                const int bt = m0 + wm + mt * 16 + quad * 4 + r;
                float v[4];
                #pragma unroll
                for (int nt = 0; nt < 4; ++nt) v[nt] = acc[mt][nt][r];
                float ss = v[0] * v[0] + v[1] * v[1] + v[2] * v[2] + v[3] * v[3];
                #pragma unroll
                for (int off = 1; off < 16; off <<= 1)
                    ss += __shfl_xor(ss, off, 16);
                const float rstd = rsqrtf(ss * (1.0f / 64.0f) + EPSF);
                float nv[4];
                #pragma unroll
                for (int nt = 0; nt < 4; ++nt) nv[nt] = v[nt] * rstd * sc[nt];
                const float s0 = sinp[bt * 32 + l15];
                const float c0 = cosp[bt * 32 + l15];
                const float s1 = sinp[bt * 32 + 16 + l15];
                const float c1 = cosp[bt * 32 + 16 + l15];
                float o[4];
                o[0] = (nv[0] * c0 - nv[2] * s0) * osc;
                o[1] = (nv[1] * c1 - nv[3] * s1) * osc;
                o[2] = (nv[2] * c0 + nv[0] * s0) * osc;
                o[3] = (nv[3] * c1 + nv[1] * s1) * osc;
                #pragma unroll
                for (int nt = 0; nt < 4; ++nt) {
                    const size_t off = (size_t)bt * rowstride + colbase + nt * 16 + l15;
                    const u16 hi = f2bf(o[nt]);
                    oh[off] = hi;
                    ol[off] = f2bf(o[nt] - bf2f(hi));
                }
            }
    } else {
        // ---- V: bf16 split, stored transposed: Vt[(b*4+g)*64+d][t] ----
        const int g = (gn0 - 1280) >> 6;
        const int b = (m0 + wm) >> 11;
        const int tb = ((m0 + wm) & 2047) + quad * 4;
        #pragma unroll
        for (int mt = 0; mt < 4; ++mt)
            #pragma unroll
            for (int nt = 0; nt < 4; ++nt) {
                const float v0 = acc[mt][nt][0], v1 = acc[mt][nt][1];
                const float v2 = acc[mt][nt][2], v3 = acc[mt][nt][3];
                ushort4 hv, lv;
                hv.x = f2bf(v0); hv.y = f2bf(v1); hv.z = f2bf(v2); hv.w = f2bf(v3);
                lv.x = f2bf(v0 - bf2f(hv.x)); lv.y = f2bf(v1 - bf2f(hv.y));
                lv.z = f2bf(v2 - bf2f(hv.z)); lv.w = f2bf(v3 - bf2f(hv.w));
                const size_t off =
                    ((size_t)((b * 4 + g) * 64 + nt * 16 + l15)) * Tseq + tb + mt * 16;
                *reinterpret_cast<ushort4*>(&Vth[off]) = hv;
                *reinterpret_cast<ushort4*>(&Vtl[off]) = lv;
            }
    }
}

// ---------------------------------------------------------------------------
// Fused gate/up GEMM — EXACT r10/r13 structure (256x128 tile, 512 thr, 2x4
// wave tiling, 4 even phases/K-step, triple-buffer, counted vmcnt(6),
// setprio). 131 us, conflicts 0, MfmaUtil 45%.
// ---------------------------------------------------------------------------
#define GU_PHASE_SYNC()                                       \
    __builtin_amdgcn_s_barrier();                             \
    asm volatile("s_waitcnt lgkmcnt(0)" ::: "memory");        \
    __builtin_amdgcn_sched_barrier(0)

#define GU_MFMA4(MBASE, AF)                                                      \
    _Pragma("unroll")                                                            \
    for (int mf = 0; mf < 4; ++mf) {                                             \
        accg[(MBASE) + mf][0] = __builtin_amdgcn_mfma_f32_16x16x32_bf16(         \
            AF[mf], bgf[0], accg[(MBASE) + mf][0], 0, 0, 0);                     \
        accu[(MBASE) + mf][0] = __builtin_amdgcn_mfma_f32_16x16x32_bf16(         \
            AF[mf], buf2[0], accu[(MBASE) + mf][0], 0, 0, 0);                    \
        accg[(MBASE) + mf][1] = __builtin_amdgcn_mfma_f32_16x16x32_bf16(         \
            AF[mf], bgf[1], accg[(MBASE) + mf][1], 0, 0, 0);                     \
        accu[(MBASE) + mf][1] = __builtin_amdgcn_mfma_f32_16x16x32_bf16(         \
            AF[mf], buf2[1], accu[(MBASE) + mf][1], 0, 0, 0);                    \
    }

__global__ __launch_bounds__(512, 2) void gateup8_kernel(
    const u16* __restrict__ Yh, const u16* __restrict__ Yl,
    const u16* __restrict__ Gw, const u16* __restrict__ Uw,
    u16* __restrict__ FF)
{
    constexpr int NK = 32;                 // K=1024 / 32
    __shared__ u16 AsH[3][256 * 32];       // 48 KB
    __shared__ u16 AsL[3][256 * 32];       // 48 KB
    __shared__ u16 Gs[3][128 * 32];        // 24 KB
    __shared__ u16 Us[3][128 * 32];        // 24 KB  -> 144 KB total, 1 blk/CU

    const int tid  = threadIdx.x;
    const int lane = tid & 63;
    const int wave = tid >> 6;
    const int wave_m = wave >> 2;          // 0..1  -> A rows wave_m*128..+127
    const int wave_n = wave & 3;           // 0..3  -> B rows wave_n*32..+31

    // XCD-aware bijective swizzle: 512 wgs = 8 xcd * 64. Per XCD: 4 n-tiles
    // (gate+up panel 2 MB -> L2-resident), consecutive idx share the m-tile.
    const int wg  = blockIdx.x;
    const int xcd = wg & 7;
    const int idx = wg >> 3;               // 0..63
    const int ntile = xcd * 4 + (idx & 3); // 0..31
    const int mtile = idx >> 2;            // 0..15
    const int m0 = mtile * 256, n0 = ntile * 128;

    const int fm = lane & 15, quad = lane >> 4;
    const int fsw = (fm >> 1) & 3;
    const int fcol = (quad ^ fsw) * 8;

    f32x4 accg[8][2], accu[8][2];
    #pragma unroll
    for (int i = 0; i < 8; ++i)
        #pragma unroll
        for (int j = 0; j < 2; ++j) {
            accg[i][j] = (f32x4){0.f, 0.f, 0.f, 0.f};
            accu[i][j] = (f32x4){0.f, 0.f, 0.f, 0.f};
        }

    // ---- staging constants (512 thr * 16 B = 8 KB per issue) ----
    const int srow = tid >> 2;             // 0..127
    const int schk = tid & 3;
    const int sw   = schk ^ ((srow >> 1) & 3);   // same for srow+128 (128%4==0)
    const u16* aSrc0 = &Yh[(size_t)(m0 + srow) * 1024 + sw * 8];
    const u16* aSrc1 = &Yh[(size_t)(m0 + srow + 128) * 1024 + sw * 8];
    const u16* lSrc0 = &Yl[(size_t)(m0 + srow) * 1024 + sw * 8];
    const u16* lSrc1 = &Yl[(size_t)(m0 + srow + 128) * 1024 + sw * 8];
    const u16* gSrc  = &Gw[(size_t)(n0 + srow) * 1024 + sw * 8];
    const u16* uSrc  = &Uw[(size_t)(n0 + srow) * 1024 + sw * 8];
    const int aDst0 = srow * 32 + schk * 8;      // bytes = tid*16 (linear)
    const int aDst1 = aDst0 + 128 * 32;

#define STAGE_AH(T, BUF) do {                                  \
        async_copy16(aSrc0 + (T) * 32, &AsH[BUF][aDst0]);      \
        async_copy16(aSrc1 + (T) * 32, &AsH[BUF][aDst1]); } while (0)
#define STAGE_AL(T, BUF) do {                                  \
        async_copy16(lSrc0 + (T) * 32, &AsL[BUF][aDst0]);      \
        async_copy16(lSrc1 + (T) * 32, &AsL[BUF][aDst1]); } while (0)
#define STAGE_B(T, BUF) do {                                   \
        async_copy16(gSrc + (T) * 32, &Gs[BUF][aDst0]);        \
        async_copy16(uSrc + (T) * 32, &Us[BUF][aDst0]); } while (0)

    // ---- fragment read offsets (u16 units) ----
    int raOff[8], rbOff[2];
    #pragma unroll
    for (int mf = 0; mf < 8; ++mf)
        raOff[mf] = (wave_m * 128 + mf * 16 + fm) * 32 + fcol;
    #pragma unroll
    for (int nf = 0; nf < 2; ++nf)
        rbOff[nf] = (wave_n * 32 + nf * 16 + fm) * 32 + fcol;

    // ---- prologue: fill buffers 0 and 1 (12 loads in flight -> wait 6) ----
    STAGE_AH(0, 0); STAGE_AL(0, 0); STAGE_B(0, 0);
    STAGE_AH(1, 1); STAGE_AL(1, 1); STAGE_B(1, 1);
    asm volatile("s_waitcnt vmcnt(6)" ::: "memory");
    __builtin_amdgcn_s_barrier();

    int bcur = 0, bnxt = 2;
    #pragma unroll 1
    for (int t = 0; t < NK; ++t) {
        const bool pf = (t + 2 < NK);
        bf16x8 bgf[2], buf2[2];

        // ---- phase 0: B frags + A-hi m0-3 ; stage A-hi(t+2) ----
        {
            #pragma unroll
            for (int nf = 0; nf < 2; ++nf) {
                bgf[nf]  = *reinterpret_cast<const bf16x8*>(&Gs[bcur][rbOff[nf]]);
                buf2[nf] = *reinterpret_cast<const bf16x8*>(&Us[bcur][rbOff[nf]]);
            }
            bf16x8 af[4];
            #pragma unroll
            for (int mf = 0; mf < 4; ++mf)
                af[mf] = *reinterpret_cast<const bf16x8*>(&AsH[bcur][raOff[mf]]);
            if (pf) STAGE_AH(t + 2, bnxt);
            GU_PHASE_SYNC();
            __builtin_amdgcn_s_setprio(1);
            GU_MFMA4(0, af);
            __builtin_amdgcn_s_setprio(0);
            __builtin_amdgcn_s_barrier();
        }
        // ---- phase 1: A-hi m4-7 ; stage A-lo(t+2) ----
        {
            bf16x8 af[4];
            #pragma unroll
            for (int mf = 0; mf < 4; ++mf)
                af[mf] = *reinterpret_cast<const bf16x8*>(&AsH[bcur][raOff[mf + 4]]);
            if (pf) STAGE_AL(t + 2, bnxt);
            GU_PHASE_SYNC();
            __builtin_amdgcn_s_setprio(1);
            GU_MFMA4(4, af);
            __builtin_amdgcn_s_setprio(0);
            __builtin_amdgcn_s_barrier();
        }
        // ---- phase 2: A-lo m0-3 ; stage B(t+2) ----
        {
            bf16x8 af[4];
            #pragma unroll
            for (int mf = 0; mf < 4; ++mf)
                af[mf] = *reinterpret_cast<const bf16x8*>(&AsL[bcur][raOff[mf]]);
            if (pf) STAGE_B(t + 2, bnxt);
            GU_PHASE_SYNC();
            __builtin_amdgcn_s_setprio(1);
            GU_MFMA4(0, af);
            __builtin_amdgcn_s_setprio(0);
            __builtin_amdgcn_s_barrier();
        }
        // ---- phase 3: A-lo m4-7 ; counted vmcnt, never 0 until the tail ----
        {
            bf16x8 af[4];
            #pragma unroll
            for (int mf = 0; mf < 4; ++mf)
                af[mf] = *reinterpret_cast<const bf16x8*>(&AsL[bcur][raOff[mf + 4]]);
            GU_PHASE_SYNC();
            __builtin_amdgcn_s_setprio(1);
            GU_MFMA4(4, af);
            __builtin_amdgcn_s_setprio(0);
            if (t + 2 < NK) {
                asm volatile("s_waitcnt vmcnt(6)" ::: "memory");
            } else if (t + 1 < NK) {
                asm volatile("s_waitcnt vmcnt(0)" ::: "memory");
            }
            __builtin_amdgcn_s_barrier();
        }

        bcur = (bcur == 2) ? 0 : bcur + 1;
        bnxt = (bnxt == 2) ? 0 : bnxt + 1;
    }
#undef STAGE_AH
#undef STAGE_AL
#undef STAGE_B

    // ---- epilogue: silu(g)*u -> bf16 ----
    const int cr = quad * 4;
    #pragma unroll
    for (int mf = 0; mf < 8; ++mf)
        #pragma unroll
        for (int nf = 0; nf < 2; ++nf)
            #pragma unroll
            for (int r = 0; r < 4; ++r) {
                const int gm = m0 + wave_m * 128 + mf * 16 + cr + r;
                const int gn = n0 + wave_n * 32 + nf * 16 + fm;
                const float g = accg[mf][nf][r];
                const float ff = (g / (1.0f + __expf(-g))) * accu[mf][nf][r];
                FF[(size_t)gm * Ff + gn] = f2bf(ff);
            }
}

// ---------------------------------------------------------------------------
// MFMA flash attention, r17: paired-window 8-wave blocks (r16) + BALANCED
// per-CU load. r16's heavy-first mapping pairs pair-63 (33 iters) with
// pair-31 (17) on one CU (blocks x and x+256 share a CU under round-robin
// dispatch: same XCD since 256%8==0, same CU slot since (x/8+32)%32 wraps)
// -> max-CU 50 iters vs avg 33. r17 mapping: blocks 0..255 -> pairs 63..32
// descending, blocks 256..511 -> pairs 0..31 ascending; each CU's two blocks
// sum to EXACTLY 33 iterations (parity-checked). Same block set, renumbered
// -> bitwise-identical output.
// ---------------------------------------------------------------------------
__global__ __launch_bounds__(512) void attn_mfma_kernel(
    const u16* __restrict__ Qh, const u16* __restrict__ Ql,
    const u16* __restrict__ Kh, const u16* __restrict__ Kl,
    const u16* __restrict__ Vth, const u16* __restrict__ Vtl,
    u16* __restrict__ AOh, u16* __restrict__ AOl)
{
    __shared__ u16 KsH[64 * 72];
    __shared__ u16 KsL[64 * 72];
    __shared__ u16 VsH[64 * 72];
    __shared__ u16 VsL[64 * 72];
    __shared__ u16 Ps[8][16 * 72];     // total LDS 55.3 KB -> 2 blocks/CU

    const int tid = threadIdx.x;
    const int wave = tid >> 6, lane = tid & 63;
    const int l15 = lane & 15, quad = lane >> 4;

    const int bg = blockIdx.x & 7;
    const int b = bg >> 2, g = bg & 3;
    const int pr = blockIdx.x >> 3;                // 0..63
    const int pair = (pr < 32) ? (63 - pr) : (pr - 32);  // balanced mapping
    const int win = pair * 2 + (wave >> 2);        // this wave's window
    const int t0 = win * 16;
    const int h = g * 4 + (wave & 3);

    bf16x8 qh[2], ql[2];
    {
        const size_t qrow = (size_t)(b * Tseq + t0 + l15) * 1024 + h * 64;
        #pragma unroll
        for (int ks = 0; ks < 2; ++ks) {
            qh[ks] = *reinterpret_cast<const bf16x8*>(&Qh[qrow + ks * 32 + quad * 8]);
            ql[ks] = *reinterpret_cast<const bf16x8*>(&Ql[qrow + ks * 32 + quad * 8]);
        }
    }

    // staging: 512 threads, 1 uint4 per array each. srow 0..63, scol 0..56.
    const int srow = tid >> 3;
    const int scol = (tid & 7) * 8;
    const size_t kgb = (size_t)(b * Tseq) * 256 + g * 64 + scol;
    const size_t vgb = (size_t)(bg * 64 + srow) * Tseq + scol;

    // shared iteration count for the pair (identical for both windows)
    const int nit = (pair * 32 + 16) / 64 + 1;

    uint4 ck0, cl0, cv0, cw0;
    {
        const size_t ka = kgb + (size_t)srow * 256;
        ck0 = *reinterpret_cast<const uint4*>(&Kh[ka]);
        cl0 = *reinterpret_cast<const uint4*>(&Kl[ka]);
        cv0 = *reinterpret_cast<const uint4*>(&Vth[vgb]);
        cw0 = *reinterpret_cast<const uint4*>(&Vtl[vgb]);
    }

    f32x4 oacc[4];
    #pragma unroll
    for (int nt = 0; nt < 4; ++nt) oacc[nt] = (f32x4){0.f, 0.f, 0.f, 0.f};
    float m_r[4], l_r[4];
    #pragma unroll
    for (int r = 0; r < 4; ++r) { m_r[r] = -1e30f; l_r[r] = 0.0f; }

    u16* psw = &Ps[wave][0];
    const int lb = srow * 72 + scol;

    for (int it = 0; it < nit; ++it) {
        const int s0 = it * 64;
        const bool diag = (it == nit - 1);

        __syncthreads();
        *reinterpret_cast<uint4*>(&KsH[lb]) = ck0;
        *reinterpret_cast<uint4*>(&KsL[lb]) = cl0;
        *reinterpret_cast<uint4*>(&VsH[lb]) = cv0;
        *reinterpret_cast<uint4*>(&VsL[lb]) = cw0;
        if (it + 1 < nit) {
            const size_t ka = kgb + (size_t)(s0 + 64 + srow) * 256;
            ck0 = *reinterpret_cast<const uint4*>(&Kh[ka]);
            cl0 = *reinterpret_cast<const uint4*>(&Kl[ka]);
            const size_t va = vgb + s0 + 64;
            cv0 = *reinterpret_cast<const uint4*>(&Vth[va]);
            cw0 = *reinterpret_cast<const uint4*>(&Vtl[va]);
        }
        __syncthreads();

        f32x4 sacc[4];
        #pragma unroll
        for (int nt = 0; nt < 4; ++nt) sacc[nt] = (f32x4){0.f, 0.f, 0.f, 0.f};

        #pragma unroll
        for (int ks = 0; ks < 2; ++ks) {
            bf16x8 kfh[4], kfl[4];
            #pragma unroll
            for (int nt = 0; nt < 4; ++nt) {
                const int a = (nt * 16 + l15) * 72 + ks * 32 + quad * 8;
                kfh[nt] = *reinterpret_cast<const bf16x8*>(&KsH[a]);
                kfl[nt] = *reinterpret_cast<const bf16x8*>(&KsL[a]);
            }
            #pragma unroll
            for (int nt = 0; nt < 4; ++nt) {
                sacc[nt] = __builtin_amdgcn_mfma_f32_16x16x32_bf16(qh[ks], kfh[nt], sacc[nt], 0, 0, 0);
                sacc[nt] = __builtin_amdgcn_mfma_f32_16x16x32_bf16(ql[ks], kfh[nt], sacc[nt], 0, 0, 0);
                sacc[nt] = __builtin_amdgcn_mfma_f32_16x16x32_bf16(qh[ks], kfl[nt], sacc[nt], 0, 0, 0);
            }
        }

        if (diag) {
            #pragma unroll
            for (int nt = 0; nt < 4; ++nt) {
                const int sg = s0 + nt * 16 + l15;
                #pragma unroll
                for (int r = 0; r < 4; ++r)
                    if (sg > t0 + quad * 4 + r) sacc[nt][r] = -1e30f;
            }
        }

        #pragma unroll
        for (int r = 0; r < 4; ++r) {
            float mx = fmaxf(fmaxf(sacc[0][r], sacc[1][r]),
                             fmaxf(sacc[2][r], sacc[3][r]));
            #pragma unroll
            for (int off = 1; off < 16; off <<= 1)
                mx = fmaxf(mx, __shfl_xor(mx, off, 16));
            const float mnew = fmaxf(m_r[r], mx);
            const float alpha = __expf(m_r[r] - mnew);
            m_r[r] = mnew;

            float rs = 0.0f;
            #pragma unroll
            for (int nt = 0; nt < 4; ++nt) {
                const float p = __expf(sacc[nt][r] - mnew);
                sacc[nt][r] = p;
                rs += p;
            }
            #pragma unroll
            for (int off = 1; off < 16; off <<= 1)
                rs += __shfl_xor(rs, off, 16);
            l_r[r] = l_r[r] * alpha + rs;
            #pragma unroll
            for (int nt = 0; nt < 4; ++nt) oacc[nt][r] *= alpha;
            #pragma unroll
            for (int nt = 0; nt < 4; ++nt)
                psw[(quad * 4 + r) * 72 + nt * 16 + l15] = f2bf(sacc[nt][r]);
        }

        #pragma unroll
        for (int ks = 0; ks < 2; ++ks) {
            const bf16x8 pa = *reinterpret_cast<const bf16x8*>(
                &psw[l15 * 72 + ks * 32 + quad * 8]);
            bf16x8 vfh[4], vfl[4];
            #pragma unroll
            for (int nt = 0; nt < 4; ++nt) {
                const int a = (nt * 16 + l15) * 72 + ks * 32 + quad * 8;
                vfh[nt] = *reinterpret_cast<const bf16x8*>(&VsH[a]);
                vfl[nt] = *reinterpret_cast<const bf16x8*>(&VsL[a]);
            }
            #pragma unroll
            for (int nt = 0; nt < 4; ++nt) {
                oacc[nt] = __builtin_amdgcn_mfma_f32_16x16x32_bf16(pa, vfh[nt], oacc[nt], 0, 0, 0);
                oacc[nt] = __builtin_amdgcn_mfma_f32_16x16x32_bf16(pa, vfl[nt], oacc[nt], 0, 0, 0);
            }
        }
    }

    #pragma unroll
    for (int r = 0; r < 4; ++r) {
        const float inv = 1.0f / l_r[r];
        const size_t orow = (size_t)(b * Tseq + t0 + quad * 4 + r) * 1024 + h * 64;
        #pragma unroll
        for (int nt = 0; nt < 4; ++nt) {
            const float o = oacc[nt][r] * inv;
            const u16 hi = f2bf(o);
            AOh[orow + nt * 16 + l15] = hi;
            AOl[orow + nt * 16 + l15] = f2bf(o - bf2f(hi));
        }
    }
}

// ---------------------------------------------------------------------------
// Host launcher
// ---------------------------------------------------------------------------
extern "C" void kernel_launch(void* const* d_in, const int* in_sizes, int n_in,
                              void* d_out, int out_size, void* d_ws,
                              size_t ws_size, hipStream_t stream)
{
    const float* hidden = (const float*)d_in[0];
    const float* sinp   = (const float*)d_in[1];
    const float* cosp   = (const float*)d_in[2];
    // d_in[3] = mask — causal, handled analytically
    const float* ln1    = (const float*)d_in[4];
    const float* ln2    = (const float*)d_in[5];
    const float* qn     = (const float*)d_in[6];
    const float* kn     = (const float*)d_in[7];
    const float* q_w    = (const float*)d_in[8];
    const float* k_w    = (const float*)d_in[9];
    const float* v_w    = (const float*)d_in[10];
    const float* o_w    = (const float*)d_in[11];
    const float* gate_w = (const float*)d_in[12];
    const float* up_w   = (const float*)d_in[13];
    const float* down_w = (const float*)d_in[14];
    float* out = (float*)d_out;

    // ---- workspace layout (116.4 MB; capacity >= 120.6 MB proven r8) ----
    char* base = (char*)d_ws;
    u16*   OTh  = (u16*)(base);                //  2 MB
    u16*   OTl  = (u16*)(base + 2097152);      //  2 MB
    u16*   GTh  = (u16*)(base + 4194304);      //  8 MB
    u16*   UTh  = (u16*)(base + 12582912);     //  8 MB
    u16*   DTh  = (u16*)(base + 20971520);     //  8 MB
    u16*   QKVT = (u16*)(base + 29360128);     //  3 MB
    u16*   Xh   = (u16*)(base + 32505856);     //  8 MB
    u16*   Qbh  = (u16*)(base + 40894464);     //  8 MB
    u16*   Qbl  = (u16*)(base + 49283072);     //  8 MB
    u16*   Kbh  = (u16*)(base + 57671680);     //  2 MB
    u16*   Kbl  = (u16*)(base + 59768832);     //  2 MB
    u16*   Vth  = (u16*)(base + 61865984);     //  2 MB
    u16*   Vtl  = (u16*)(base + 63963136);     //  2 MB
    u16*   AOh  = (u16*)(base + 66060288);     //  8 MB
    u16*   AOl  = (u16*)(base + 74448896);     //  8 MB
    u16*   FFh  = (u16*)(base + 82837504);     // 32 MB (end 116,391,936)

    // aliases (lifetime-checked):
    float* H2 = (float*)Qbh;   // 16 MB over Qbh+Qbl (Q dead post-attn)
    u16*   Yh = Kbh;           //  8 MB over Kbh..Vtl (K/V dead post-attn)
    u16*   Yl = AOh;           //  8 MB over AOh (AO dead post-o-proj)

    // 0. all weight prep + fused rmsnorm(ln1) in one launch (r17)
    wprep_all_kernel<<<14848 + Mrows, 256, 0, stream>>>(
        q_w, k_w, v_w, o_w, gate_w, up_w, down_w, hidden, ln1,
        QKVT, OTh, OTl, GTh, UTh, DTh, Xh);

    // 1. fused qkv projection + qknorm + rope + split + V-transpose (r14 pipe)
    qkv_fused_kernel<<<dim3(12, 32), 256, 0, stream>>>(
        Xh, QKVT, qn, kn, sinp, cosp, Qbh, Qbl, Kbh, Kbl, Vth, Vtl);

    // 2. MFMA flash attention — r17 balanced paired-window blocks (512)
    attn_mfma_kernel<<<Bsz * Gg * (Tseq / 32), 512, 0, stream>>>(
        Qbh, Qbl, Kbh, Kbl, Vth, Vtl, AOh, AOl);

    // 3. hidden2 = hidden + attn @ o_w  (split x split) — BN=128 (r13-exact)
    mfma_gemm_pipe<32, 128, 1, 1, 1><<<dim3(8, 32), 256, 0, stream>>>(
        AOh, AOl, OTh, OTl, hidden, H2, Mrows, Dmod);

    // 4. y = rmsnorm(hidden2, ln2) -> bf16 hi/lo
    rmsnorm_split_kernel<1><<<Mrows, 256, 0, stream>>>(H2, ln2, Yh, Yl);

    // 5. ff = silu(y@gate_w) * (y@up_w) -> FF bf16 (r10/r13-exact)
    gateup8_kernel<<<512, 512, 0, stream>>>(Yh, Yl, GTh, UTh, FFh);

    // 6. out = hidden2 + ff @ down_w — BN=128 (r13-exact)
    mfma_gemm_pipe<128, 128, 0, 0, 1><<<dim3(8, 32), 256, 0, stream>>>(
        FFh, nullptr, DTh, nullptr, H2, out, Mrows, Dmod);
}

// Round 9
// 491.489 us; speedup vs baseline: 1.0326x; 1.0326x over previous
//
#include <hip/hip_runtime.h>
#include <hip/hip_bf16.h>

// Problem constants: B=2, T=2048, D=1024, H=16, G=4, K=64, F=4096
#define EPSF 1e-6f
constexpr int Bsz  = 2;
constexpr int Tseq = 2048;
constexpr int Dmod = 1024;
constexpr int Hh   = 16;
constexpr int Gg   = 4;
constexpr int Ff   = 4096;
constexpr int Mrows = Bsz * Tseq;          // 4096 tokens

typedef __attribute__((ext_vector_type(8))) short bf16x8;   // 8 bf16 (4 VGPRs)
typedef __attribute__((ext_vector_type(4))) float f32x4;
typedef unsigned short u16;

// RNE fp32 -> bf16 (bit pattern as u16)
__device__ inline u16 f2bf(float x) {
    union { float f; unsigned u; } v; v.f = x;
    unsigned r = v.u + 0x7fff + ((v.u >> 16) & 1);
    return (u16)(r >> 16);
}
__device__ inline float bf2f(u16 h) {
    union { unsigned u; float f; } v; v.u = ((unsigned)h) << 16; return v.f;
}

// Async global->LDS DMA, 16 B per lane (wave-uniform base + lane*16).
__device__ __forceinline__ void async_copy16(const u16* g, u16* l) {
    __builtin_amdgcn_global_load_lds(
        (const __attribute__((address_space(1))) void*)g,
        (__attribute__((address_space(3))) void*)l, 16, 0, 0);
}

// Bank-swizzle: LDS tiles [row][32] bf16 (64 B rows). Logical k-chunk q of row
// R stored at chunk q ^ ((R>>1)&3); staging fetches global chunk
// (lane&3)^((row>>1)&3) into linear dest lane*16; reads XOR the same term.
// Conflict-free ONLY for the 16x16 read geometry — verified r7/r10 (=0).
// The 32x32 read geometry conflicts under ANY chunk-XOR (r11/r12, 1.05e7).
//
// GEMM tile-size lesson (r15): BN=64 regressed o/down-proj ~+11us vs BN=128.
// BN=128 final. gateup stays at r10-exact (131us/45%; r11/r12 32x32 and r14
// 4x2-retile both refuted).
// Attn lessons: r16 traffic-halving pairing = neutral; r17 CU-balanced
// mapping = null (and that run had ~12% clock drift — gateup, bit-identical,
// ran 131.9->147.7us; use gateup as the cross-run anchor). r18 reverts to
// the r16 heavy-first mapping (the 487us-measured config). Attn is not
// top-5-observable; stop blind iteration on it.

// ---------------------------------------------------------------------------
// ALL weight prep in ONE launch + FUSED rmsnorm(ln1) blocks appended (r17:
// rmsnorm1 is independent of weight prep; folding it into this grid fills the
// dispatch tail instead of serializing behind it). Blocks 0..14847 = wprep,
// 14848..18943 = rmsnorm rows. Numerics of both parts unchanged.
// ---------------------------------------------------------------------------
__global__ __launch_bounds__(256) void wprep_all_kernel(
    const float* __restrict__ q_w, const float* __restrict__ k_w,
    const float* __restrict__ v_w, const float* __restrict__ o_w,
    const float* __restrict__ gate_w, const float* __restrict__ up_w,
    const float* __restrict__ down_w,
    const float* __restrict__ hidden, const float* __restrict__ ln1,
    u16* __restrict__ QKVT, u16* __restrict__ OTh, u16* __restrict__ OTl,
    u16* __restrict__ GTh, u16* __restrict__ UTh, u16* __restrict__ DTh,
    u16* __restrict__ Xh)
{
    const int bx = blockIdx.x;

    if (bx >= 14848) {
        // ---- fused rmsnorm(hidden, ln1) -> Xh, one block per token ----
        const int row = bx - 14848;
        const int tid = threadIdx.x;
        const float4 v = reinterpret_cast<const float4*>(hidden + (size_t)row * Dmod)[tid];
        float ss = v.x * v.x + v.y * v.y + v.z * v.z + v.w * v.w;
        #pragma unroll
        for (int off = 32; off; off >>= 1) ss += __shfl_xor(ss, off, 64);
        __shared__ float part[4];
        if ((tid & 63) == 0) part[tid >> 6] = ss;
        __syncthreads();
        const float tot = part[0] + part[1] + part[2] + part[3];
        const float rstd = rsqrtf(tot * (1.0f / Dmod) + EPSF);
        const float4 sc = reinterpret_cast<const float4*>(ln1)[tid];
        ushort4 h;
        h.x = f2bf(v.x * rstd * sc.x); h.y = f2bf(v.y * rstd * sc.y);
        h.z = f2bf(v.z * rstd * sc.z); h.w = f2bf(v.w * rstd * sc.w);
        *reinterpret_cast<ushort4*>(&Xh[(size_t)row * Dmod + tid * 4]) = h;
        return;
    }

    const float* W; u16* Th; u16* Tl = nullptr;
    int N, Kd, ntile, ktile, drow;
    if (bx < 1024) {
        W = q_w; N = 1024; Kd = 1024; ntile = bx & 31; ktile = bx >> 5;
        Th = QKVT; drow = ntile * 32;
    } else if (bx < 1280) {
        const int i = bx - 1024;
        W = k_w; N = 256; Kd = 1024; ntile = i & 7; ktile = i >> 3;
        Th = QKVT; drow = 1024 + ntile * 32;
    } else if (bx < 1536) {
        const int i = bx - 1280;
        W = v_w; N = 256; Kd = 1024; ntile = i & 7; ktile = i >> 3;
        Th = QKVT; drow = 1280 + ntile * 32;
    } else if (bx < 2560) {
        const int i = bx - 1536;
        W = o_w; N = 1024; Kd = 1024; ntile = i & 31; ktile = i >> 5;
        Th = OTh; Tl = OTl; drow = ntile * 32;
    } else if (bx < 6656) {
        const int i = bx - 2560;
        W = gate_w; N = 4096; Kd = 1024; ntile = i & 127; ktile = i >> 7;
        Th = GTh; drow = ntile * 32;
    } else if (bx < 10752) {
        const int i = bx - 6656;
        W = up_w; N = 4096; Kd = 1024; ntile = i & 127; ktile = i >> 7;
        Th = UTh; drow = ntile * 32;
    } else {
        const int i = bx - 10752;
        W = down_w; N = 1024; Kd = 4096; ntile = i & 31; ktile = i >> 5;
        Th = DTh; drow = ntile * 32;
    }
    const int n0 = ntile * 32, k0 = ktile * 32;

    __shared__ float tile[32][33];
    const int r = threadIdx.x >> 3, c4 = (threadIdx.x & 7) * 4;
    const float4 v = *reinterpret_cast<const float4*>(&W[(size_t)(k0 + r) * N + n0 + c4]);
    tile[r][c4 + 0] = v.x; tile[r][c4 + 1] = v.y;
    tile[r][c4 + 2] = v.z; tile[r][c4 + 3] = v.w;
    __syncthreads();
    const int nl = threadIdx.x >> 3, kq = (threadIdx.x & 7) * 4;
    float x0 = tile[kq + 0][nl], x1 = tile[kq + 1][nl];
    float x2 = tile[kq + 2][nl], x3 = tile[kq + 3][nl];
    ushort4 h;
    h.x = f2bf(x0); h.y = f2bf(x1); h.z = f2bf(x2); h.w = f2bf(x3);
    *reinterpret_cast<ushort4*>(&Th[(size_t)(drow + nl) * Kd + k0 + kq]) = h;
    if (Tl) {
        ushort4 l;
        l.x = f2bf(x0 - bf2f(h.x)); l.y = f2bf(x1 - bf2f(h.y));
        l.z = f2bf(x2 - bf2f(h.z)); l.w = f2bf(x3 - bf2f(h.w));
        *reinterpret_cast<ushort4*>(&Tl[(size_t)(drow + nl) * Kd + k0 + kq]) = l;
    }
}

// ---------------------------------------------------------------------------
// RMSNorm over D=1024 -> bf16 hi (+ optional lo). One block per token.
// (Standalone instance used for ln2; ln1 instance is fused into wprep.)
// ---------------------------------------------------------------------------
template <int LO>
__global__ __launch_bounds__(256) void rmsnorm_split_kernel(
    const float* __restrict__ x, const float* __restrict__ scale,
    u16* __restrict__ oh, u16* __restrict__ ol)
{
    const int row = blockIdx.x;
    const int tid = threadIdx.x;
    const float4 v = reinterpret_cast<const float4*>(x + (size_t)row * Dmod)[tid];
    float ss = v.x * v.x + v.y * v.y + v.z * v.z + v.w * v.w;
    #pragma unroll
    for (int off = 32; off; off >>= 1) ss += __shfl_xor(ss, off, 64);
    __shared__ float part[4];
    if ((tid & 63) == 0) part[tid >> 6] = ss;
    __syncthreads();
    const float tot = part[0] + part[1] + part[2] + part[3];
    const float rstd = rsqrtf(tot * (1.0f / Dmod) + EPSF);
    const float4 sc = reinterpret_cast<const float4*>(scale)[tid];
    float o0 = v.x * rstd * sc.x, o1 = v.y * rstd * sc.y;
    float o2 = v.z * rstd * sc.z, o3 = v.w * rstd * sc.w;
    ushort4 h;
    h.x = f2bf(o0); h.y = f2bf(o1); h.z = f2bf(o2); h.w = f2bf(o3);
    *reinterpret_cast<ushort4*>(&oh[(size_t)row * Dmod + tid * 4]) = h;
    if (LO) {
        ushort4 l;
        l.x = f2bf(o0 - bf2f(h.x)); l.y = f2bf(o1 - bf2f(h.y));
        l.z = f2bf(o2 - bf2f(h.z)); l.w = f2bf(o3 - bf2f(h.w));
        *reinterpret_cast<ushort4*>(&ol[(size_t)row * Dmod + tid * 4]) = l;
    }
}

// ---------------------------------------------------------------------------
// Split-bf16 MFMA GEMM, r13 pipeline (BN kept as template param; BN=128 is
// the proven config — see tile-size lesson above).
// ---------------------------------------------------------------------------
template <int NKT, int BN, int ASPLIT, int BSPLIT, int RES>
__global__ __launch_bounds__(256, 2) void mfma_gemm_pipe(
    const u16* __restrict__ Ah, const u16* __restrict__ Al,
    const u16* __restrict__ Bh, const u16* __restrict__ Bl,
    const float* __restrict__ res, float* __restrict__ C,
    int M, int N)
{
    constexpr int Kd = NKT * 32;
    constexpr int NT = (BN / 2) / 16;                 // n-frags per wave
    constexpr int NI = 2 + 2 * ASPLIT + (BN / 64) + (BN / 64) * BSPLIT;
    static_assert((NKT - 2) % 3 == 0, "main loop unroll-3");

    __shared__ u16 AsH[3][128 * 32];                  // 24 KB
    __shared__ u16 BsH[3][BN * 32];                   // 24/12 KB
    __shared__ u16 AsL[ASPLIT ? 3 : 1][128 * 32];     // 24/8 KB
    __shared__ u16 BsL[BSPLIT ? 3 : 1][BN * 32];      // 24|12 / 8|4 KB

    const int tid = threadIdx.x;
    const int lane = tid & 63, wave = tid >> 6;
    const int wm = (wave >> 1) * 64, wn = (wave & 1) * (BN / 2);
    const int m0 = blockIdx.y * 128, n0 = blockIdx.x * BN;
    const int fm = lane & 15, quad = lane >> 4;
    const int fsw = (fm >> 1) & 3;
    const int fcol = (quad ^ fsw) * 8;

    f32x4 acc[4][NT];
    #pragma unroll
    for (int i = 0; i < 4; ++i)
        #pragma unroll
        for (int j = 0; j < NT; ++j) acc[i][j] = (f32x4){0.f, 0.f, 0.f, 0.f};

    // staging: 256 thr * 16 B = 4 KB/issue; 128x32 tile = 2 issues, 64x32 = 1
    const int srow = tid >> 2;             // 0..63
    const int schk = tid & 3;
    const int sw   = schk ^ ((srow >> 1) & 3);   // f(srow+64)==f(srow)
    const u16* aS0 = &Ah[(size_t)(m0 + srow) * Kd + sw * 8];
    const u16* aS1 = &Ah[(size_t)(m0 + srow + 64) * Kd + sw * 8];
    const u16* bS0 = &Bh[(size_t)(n0 + srow) * Kd + sw * 8];
    const u16* bS1 = (BN == 128) ? &Bh[(size_t)(n0 + srow + 64) * Kd + sw * 8] : nullptr;
    const u16* alS0 = ASPLIT ? &Al[(size_t)(m0 + srow) * Kd + sw * 8] : nullptr;
    const u16* alS1 = ASPLIT ? &Al[(size_t)(m0 + srow + 64) * Kd + sw * 8] : nullptr;
    const u16* blS0 = BSPLIT ? &Bl[(size_t)(n0 + srow) * Kd + sw * 8] : nullptr;
    const u16* blS1 = (BSPLIT && BN == 128) ? &Bl[(size_t)(n0 + srow + 64) * Kd + sw * 8] : nullptr;
    const int dst0 = srow * 32 + schk * 8;       // bytes = tid*16 (linear)
    const int dst1 = dst0 + 64 * 32;

#define PSTAGE(T, BUF) do {                                                  \
        async_copy16(aS0 + (T) * 32, &AsH[BUF][dst0]);                       \
        async_copy16(aS1 + (T) * 32, &AsH[BUF][dst1]);                       \
        if (ASPLIT) {                                                        \
            async_copy16(alS0 + (T) * 32, &AsL[BUF][dst0]);                  \
            async_copy16(alS1 + (T) * 32, &AsL[BUF][dst1]);                  \
        }                                                                    \
        async_copy16(bS0 + (T) * 32, &BsH[BUF][dst0]);                       \
        if (BN == 128) async_copy16(bS1 + (T) * 32, &BsH[BUF][dst1]);        \
        if (BSPLIT) {                                                        \
            async_copy16(blS0 + (T) * 32, &BsL[BUF][dst0]);                  \
            if (BN == 128) async_copy16(blS1 + (T) * 32, &BsL[BUF][dst1]);   \
        }                                                                    \
    } while (0)

// GATE: 1 = steady-state counted wait vmcnt(NI), 0 = drain, -1 = none.
// Counting: at the gate, outstanding = t+1's NI (older) + t+2's NI (younger);
// vmcnt(NI) completes all of t+1's (FIFO, m135).
#define PGATE(GATE) do {                                                     \
        if ((GATE) == 1) {                                                   \
            if constexpr (NI == 3)                                           \
                asm volatile("s_waitcnt vmcnt(3)" ::: "memory");             \
            else if constexpr (NI == 4)                                      \
                asm volatile("s_waitcnt vmcnt(4)" ::: "memory");             \
            else if constexpr (NI == 6)                                      \
                asm volatile("s_waitcnt vmcnt(6)" ::: "memory");             \
            else                                                             \
                asm volatile("s_waitcnt vmcnt(8)" ::: "memory");             \
        } else if ((GATE) == 0) {                                            \
            asm volatile("s_waitcnt vmcnt(0)" ::: "memory");                 \
        }                                                                    \
    } while (0)

#define PSTEP(BC, BN_, T, PF, GATE) do {                                     \
    bf16x8 ah[4], bh[NT], al[4], bl[NT];                                     \
    _Pragma("unroll")                                                        \
    for (int t = 0; t < 4; ++t) {                                            \
        const int ra = (wm + t * 16 + fm) * 32 + fcol;                       \
        ah[t] = *reinterpret_cast<const bf16x8*>(&AsH[BC][ra]);              \
        if (ASPLIT) al[t] = *reinterpret_cast<const bf16x8*>(&AsL[BC][ra]);  \
    }                                                                        \
    _Pragma("unroll")                                                        \
    for (int t = 0; t < NT; ++t) {                                           \
        const int rb = (wn + t * 16 + fm) * 32 + fcol;                       \
        bh[t] = *reinterpret_cast<const bf16x8*>(&BsH[BC][rb]);              \
        if (BSPLIT) bl[t] = *reinterpret_cast<const bf16x8*>(&BsL[BC][rb]);  \
    }                                                                        \
    if (PF) PSTAGE((T) + 2, BN_);                                            \
    __builtin_amdgcn_s_barrier();                                            \
    asm volatile("s_waitcnt lgkmcnt(0)" ::: "memory");                       \
    __builtin_amdgcn_sched_barrier(0);                                       \
    __builtin_amdgcn_s_setprio(1);                                           \
    _Pragma("unroll")                                                        \
    for (int mt = 0; mt < 4; ++mt)                                           \
        _Pragma("unroll")                                                    \
        for (int nt = 0; nt < NT; ++nt) {                                    \
            acc[mt][nt] = __builtin_amdgcn_mfma_f32_16x16x32_bf16(           \
                ah[mt], bh[nt], acc[mt][nt], 0, 0, 0);                       \
            if (BSPLIT)                                                      \
                acc[mt][nt] = __builtin_amdgcn_mfma_f32_16x16x32_bf16(       \
                    ah[mt], bl[nt], acc[mt][nt], 0, 0, 0);                   \
            if (ASPLIT)                                                      \
                acc[mt][nt] = __builtin_amdgcn_mfma_f32_16x16x32_bf16(       \
                    al[mt], bh[nt], acc[mt][nt], 0, 0, 0);                   \
        }                                                                    \
    __builtin_amdgcn_s_setprio(0);                                           \
    PGATE(GATE);                                                             \
    __builtin_amdgcn_s_barrier();                                            \
} while (0)

    // prologue: fill buffers 0 and 1 (2*NI in flight -> wait NI = buf0 done)
    PSTAGE(0, 0);
    PSTAGE(1, 1);
    PGATE(1);
    __builtin_amdgcn_s_barrier();

    #pragma unroll 1
    for (int t3 = 0; t3 < NKT - 2; t3 += 3) {
        PSTEP(0, 2, t3 + 0, true, 1);
        PSTEP(1, 0, t3 + 1, true, 1);
        PSTEP(2, 1, t3 + 2, true, 1);
    }
    // tail: t=NKT-2 (buf0, drain last loads), t=NKT-1 (buf1, nothing left)
    PSTEP(0, 2, NKT - 2, false, 0);
    PSTEP(1, 0, NKT - 1, false, -1);

#undef PSTEP
#undef PGATE
#undef PSTAGE

    const int cr = (lane >> 4) * 4, cn = lane & 15;
    #pragma unroll
    for (int mt = 0; mt < 4; ++mt)
        #pragma unroll
        for (int nt = 0; nt < NT; ++nt)
            #pragma unroll
            for (int r = 0; r < 4; ++r) {
                const int gm = m0 + wm + mt * 16 + cr + r;
                const int gn = n0 + wn + nt * 16 + cn;
                float v = acc[mt][nt][r];
                if (RES) v += res[(size_t)gm * N + gn];
                C[(size_t)gm * N + gn] = v;
            }
}

// ---------------------------------------------------------------------------
// Fused QKV GEMM + qk-norm + RoPE + bf16 split epilogue; V stored TRANSPOSED.
// r14: K-loop uses the r13-proven pipelined structure (triple buffer, counted
// vmcnt(4), setprio). Proven ~-13us in r14's bench. Epilogue unchanged.
// ---------------------------------------------------------------------------
__global__ __launch_bounds__(256, 2) void qkv_fused_kernel(
    const u16* __restrict__ Ah, const u16* __restrict__ Bh,
    const float* __restrict__ qn, const float* __restrict__ kn,
    const float* __restrict__ sinp, const float* __restrict__ cosp,
    u16* __restrict__ Qbh, u16* __restrict__ Qbl,
    u16* __restrict__ Kbh, u16* __restrict__ Kbl,
    u16* __restrict__ Vth, u16* __restrict__ Vtl)
{
    constexpr int Kd = 1024;
    constexpr int NKT = 32;
    __shared__ u16 As[3][128 * 32];    // 24 KB
    __shared__ u16 Bs[3][128 * 32];    // 24 KB -> 48 KB total

    const int tid = threadIdx.x;
    const int lane = tid & 63, wave = tid >> 6;
    const int wm = (wave >> 1) * 64, wn = (wave & 1) * 64;
    const int m0 = blockIdx.y * 128, n0 = blockIdx.x * 128;
    const int fm = lane & 15, quad = lane >> 4;
    const int fsw = (fm >> 1) & 3;
    const int fcol = ((quad ^ fsw) * 8);

    f32x4 acc[4][4];
    #pragma unroll
    for (int i = 0; i < 4; ++i)
        #pragma unroll
        for (int j = 0; j < 4; ++j) acc[i][j] = (f32x4){0.f, 0.f, 0.f, 0.f};

    const int srow = tid >> 2;             // 0..63
    const int schk = tid & 3;
    const int sw   = schk ^ ((srow >> 1) & 3);
    const u16* aS0 = &Ah[(size_t)(m0 + srow) * Kd + sw * 8];
    const u16* aS1 = &Ah[(size_t)(m0 + srow + 64) * Kd + sw * 8];
    const u16* bS0 = &Bh[(size_t)(n0 + srow) * Kd + sw * 8];
    const u16* bS1 = &Bh[(size_t)(n0 + srow + 64) * Kd + sw * 8];
    const int dst0 = srow * 32 + schk * 8;
    const int dst1 = dst0 + 64 * 32;

#define QSTAGE(T, BUF) do {                                                  \
        async_copy16(aS0 + (T) * 32, &As[BUF][dst0]);                        \
        async_copy16(aS1 + (T) * 32, &As[BUF][dst1]);                        \
        async_copy16(bS0 + (T) * 32, &Bs[BUF][dst0]);                        \
        async_copy16(bS1 + (T) * 32, &Bs[BUF][dst1]);                        \
    } while (0)

#define QSTEP(BC, BN, T, PF, GATE) do {                                      \
    bf16x8 ah[4], bh[4];                                                     \
    _Pragma("unroll")                                                        \
    for (int t = 0; t < 4; ++t) {                                            \
        ah[t] = *reinterpret_cast<const bf16x8*>(                            \
            &As[BC][(wm + t * 16 + fm) * 32 + fcol]);                        \
        bh[t] = *reinterpret_cast<const bf16x8*>(                            \
            &Bs[BC][(wn + t * 16 + fm) * 32 + fcol]);                        \
    }                                                                        \
    if (PF) QSTAGE((T) + 2, BN);                                             \
    __builtin_amdgcn_s_barrier();                                            \
    asm volatile("s_waitcnt lgkmcnt(0)" ::: "memory");                       \
    __builtin_amdgcn_sched_barrier(0);                                       \
    __builtin_amdgcn_s_setprio(1);                                           \
    _Pragma("unroll")                                                        \
    for (int mt = 0; mt < 4; ++mt)                                           \
        _Pragma("unroll")                                                    \
        for (int nt = 0; nt < 4; ++nt)                                       \
            acc[mt][nt] = __builtin_amdgcn_mfma_f32_16x16x32_bf16(           \
                ah[mt], bh[nt], acc[mt][nt], 0, 0, 0);                       \
    __builtin_amdgcn_s_setprio(0);                                           \
    if ((GATE) == 1) {                                                       \
        asm volatile("s_waitcnt vmcnt(4)" ::: "memory");                     \
    } else if ((GATE) == 0) {                                                \
        asm volatile("s_waitcnt vmcnt(0)" ::: "memory");                     \
    }                                                                        \
    __builtin_amdgcn_s_barrier();                                            \
} while (0)

    QSTAGE(0, 0);
    QSTAGE(1, 1);
    asm volatile("s_waitcnt vmcnt(4)" ::: "memory");
    __builtin_amdgcn_s_barrier();

    #pragma unroll 1
    for (int t3 = 0; t3 < NKT - 2; t3 += 3) {
        QSTEP(0, 2, t3 + 0, true, 1);
        QSTEP(1, 0, t3 + 1, true, 1);
        QSTEP(2, 1, t3 + 2, true, 1);
    }
    QSTEP(0, 2, NKT - 2, false, 0);
    QSTEP(1, 0, NKT - 1, false, -1);

#undef QSTEP
#undef QSTAGE

    const int gn0 = n0 + wn;          // wave col base, 64-aligned
    const int l15 = lane & 15;

    if (gn0 < 1280) {
        // ---- Q or K: per-head RMSNorm + RoPE + split ----
        const bool isQ = (gn0 < 1024);
        const float* nsc = isQ ? qn : kn;
        const float osc = isQ ? 0.125f : 1.0f;
        u16* __restrict__ oh = isQ ? Qbh : Kbh;
        u16* __restrict__ ol = isQ ? Qbl : Kbl;
        const int rowstride = isQ ? 1024 : 256;
        const int colbase = isQ ? gn0 : gn0 - 1024;
        float sc[4];
        #pragma unroll
        for (int nt = 0; nt < 4; ++nt) sc[nt] = nsc[nt * 16 + l15];

        #pragma unroll
        for (int mt = 0; mt < 4; ++mt)
            #pragma unroll
            for (int r = 0; r < 4; ++r) {
                const int bt = m0 + wm + mt * 16 + quad * 4 + r;
                float v[4];
                #pragma unroll
                for (int nt = 0; nt < 4; ++nt) v[nt] = acc[mt][nt][r];
                float ss = v[0] * v[0] + v[1] * v[1] + v[2] * v[2] + v[3] * v[3];
                #pragma unroll
                for (int off = 1; off < 16; off <<= 1)
                    ss += __shfl_xor(ss, off, 16);
                const float rstd = rsqrtf(ss * (1.0f / 64.0f) + EPSF);
                float nv[4];
                #pragma unroll
                for (int nt = 0; nt < 4; ++nt) nv[nt] = v[nt] * rstd * sc[nt];
                const float s0 = sinp[bt * 32 + l15];
                const float c0 = cosp[bt * 32 + l15];
                const float s1 = sinp[bt * 32 + 16 + l15];
                const float c1 = cosp[bt * 32 + 16 + l15];
                float o[4];
                o[0] = (nv[0] * c0 - nv[2] * s0) * osc;
                o[1] = (nv[1] * c1 - nv[3] * s1) * osc;
                o[2] = (nv[2] * c0 + nv[0] * s0) * osc;
                o[3] = (nv[3] * c1 + nv[1] * s1) * osc;
                #pragma unroll
                for (int nt = 0; nt < 4; ++nt) {
                    const size_t off = (size_t)bt * rowstride + colbase + nt * 16 + l15;
                    const u16 hi = f2bf(o[nt]);
                    oh[off] = hi;
                    ol[off] = f2bf(o[nt] - bf2f(hi));
                }
            }
    } else {
        // ---- V: bf16 split, stored transposed: Vt[(b*4+g)*64+d][t] ----
        const int g = (gn0 - 1280) >> 6;
        const int b = (m0 + wm) >> 11;
        const int tb = ((m0 + wm) & 2047) + quad * 4;
        #pragma unroll
        for (int mt = 0; mt < 4; ++mt)
            #pragma unroll
            for (int nt = 0; nt < 4; ++nt) {
                const float v0 = acc[mt][nt][0], v1 = acc[mt][nt][1];
                const float v2 = acc[mt][nt][2], v3 = acc[mt][nt][3];
                ushort4 hv, lv;
                hv.x = f2bf(v0); hv.y = f2bf(v1); hv.z = f2bf(v2); hv.w = f2bf(v3);
                lv.x = f2bf(v0 - bf2f(hv.x)); lv.y = f2bf(v1 - bf2f(hv.y));
                lv.z = f2bf(v2 - bf2f(hv.z)); lv.w = f2bf(v3 - bf2f(hv.w));
                const size_t off =
                    ((size_t)((b * 4 + g) * 64 + nt * 16 + l15)) * Tseq + tb + mt * 16;
                *reinterpret_cast<ushort4*>(&Vth[off]) = hv;
                *reinterpret_cast<ushort4*>(&Vtl[off]) = lv;
            }
    }
}

// ---------------------------------------------------------------------------
// Fused gate/up GEMM — EXACT r10/r13 structure (256x128 tile, 512 thr, 2x4
// wave tiling, 4 even phases/K-step, triple-buffer, counted vmcnt(6),
// setprio). 131 us, conflicts 0, MfmaUtil 45%. Cross-run CLOCK ANCHOR: if
// this kernel deviates from ~131-132us, scale all cross-run comparisons.
// ---------------------------------------------------------------------------
#define GU_PHASE_SYNC()                                       \
    __builtin_amdgcn_s_barrier();                             \
    asm volatile("s_waitcnt lgkmcnt(0)" ::: "memory");        \
    __builtin_amdgcn_sched_barrier(0)

#define GU_MFMA4(MBASE, AF)                                                      \
    _Pragma("unroll")                                                            \
    for (int mf = 0; mf < 4; ++mf) {                                             \
        accg[(MBASE) + mf][0] = __builtin_amdgcn_mfma_f32_16x16x32_bf16(         \
            AF[mf], bgf[0], accg[(MBASE) + mf][0], 0, 0, 0);                     \
        accu[(MBASE) + mf][0] = __builtin_amdgcn_mfma_f32_16x16x32_bf16(         \
            AF[mf], buf2[0], accu[(MBASE) + mf][0], 0, 0, 0);                    \
        accg[(MBASE) + mf][1] = __builtin_amdgcn_mfma_f32_16x16x32_bf16(         \
            AF[mf], bgf[1], accg[(MBASE) + mf][1], 0, 0, 0);                     \
        accu[(MBASE) + mf][1] = __builtin_amdgcn_mfma_f32_16x16x32_bf16(         \
            AF[mf], buf2[1], accu[(MBASE) + mf][1], 0, 0, 0);                    \
    }

__global__ __launch_bounds__(512, 2) void gateup8_kernel(
    const u16* __restrict__ Yh, const u16* __restrict__ Yl,
    const u16* __restrict__ Gw, const u16* __restrict__ Uw,
    u16* __restrict__ FF)
{
    constexpr int NK = 32;                 // K=1024 / 32
    __shared__ u16 AsH[3][256 * 32];       // 48 KB
    __shared__ u16 AsL[3][256 * 32];       // 48 KB
    __shared__ u16 Gs[3][128 * 32];        // 24 KB
    __shared__ u16 Us[3][128 * 32];        // 24 KB  -> 144 KB total, 1 blk/CU

    const int tid  = threadIdx.x;
    const int lane = tid & 63;
    const int wave = tid >> 6;
    const int wave_m = wave >> 2;          // 0..1  -> A rows wave_m*128..+127
    const int wave_n = wave & 3;           // 0..3  -> B rows wave_n*32..+31

    // XCD-aware bijective swizzle: 512 wgs = 8 xcd * 64. Per XCD: 4 n-tiles
    // (gate+up panel 2 MB -> L2-resident), consecutive idx share the m-tile.
    const int wg  = blockIdx.x;
    const int xcd = wg & 7;
    const int idx = wg >> 3;               // 0..63
    const int ntile = xcd * 4 + (idx & 3); // 0..31
    const int mtile = idx >> 2;            // 0..15
    const int m0 = mtile * 256, n0 = ntile * 128;

    const int fm = lane & 15, quad = lane >> 4;
    const int fsw = (fm >> 1) & 3;
    const int fcol = (quad ^ fsw) * 8;

    f32x4 accg[8][2], accu[8][2];
    #pragma unroll
    for (int i = 0; i < 8; ++i)
        #pragma unroll
        for (int j = 0; j < 2; ++j) {
            accg[i][j] = (f32x4){0.f, 0.f, 0.f, 0.f};
            accu[i][j] = (f32x4){0.f, 0.f, 0.f, 0.f};
        }

    // ---- staging constants (512 thr * 16 B = 8 KB per issue) ----
    const int srow = tid >> 2;             // 0..127
    const int schk = tid & 3;
    const int sw   = schk ^ ((srow >> 1) & 3);   // same for srow+128 (128%4==0)
    const u16* aSrc0 = &Yh[(size_t)(m0 + srow) * 1024 + sw * 8];
    const u16* aSrc1 = &Yh[(size_t)(m0 + srow + 128) * 1024 + sw * 8];
    const u16* lSrc0 = &Yl[(size_t)(m0 + srow) * 1024 + sw * 8];
    const u16* lSrc1 = &Yl[(size_t)(m0 + srow + 128) * 1024 + sw * 8];
    const u16* gSrc  = &Gw[(size_t)(n0 + srow) * 1024 + sw * 8];
    const u16* uSrc  = &Uw[(size_t)(n0 + srow) * 1024 + sw * 8];
    const int aDst0 = srow * 32 + schk * 8;      // bytes = tid*16 (linear)
    const int aDst1 = aDst0 + 128 * 32;

#define STAGE_AH(T, BUF) do {                                  \
        async_copy16(aSrc0 + (T) * 32, &AsH[BUF][aDst0]);      \
        async_copy16(aSrc1 + (T) * 32, &AsH[BUF][aDst1]); } while (0)
#define STAGE_AL(T, BUF) do {                                  \
        async_copy16(lSrc0 + (T) * 32, &AsL[BUF][aDst0]);      \
        async_copy16(lSrc1 + (T) * 32, &AsL[BUF][aDst1]); } while (0)
#define STAGE_B(T, BUF) do {                                   \
        async_copy16(gSrc + (T) * 32, &Gs[BUF][aDst0]);        \
        async_copy16(uSrc + (T) * 32, &Us[BUF][aDst0]); } while (0)

    // ---- fragment read offsets (u16 units) ----
    int raOff[8], rbOff[2];
    #pragma unroll
    for (int mf = 0; mf < 8; ++mf)
        raOff[mf] = (wave_m * 128 + mf * 16 + fm) * 32 + fcol;
    #pragma unroll
    for (int nf = 0; nf < 2; ++nf)
        rbOff[nf] = (wave_n * 32 + nf * 16 + fm) * 32 + fcol;

    // ---- prologue: fill buffers 0 and 1 (12 loads in flight -> wait 6) ----
    STAGE_AH(0, 0); STAGE_AL(0, 0); STAGE_B(0, 0);
    STAGE_AH(1, 1); STAGE_AL(1, 1); STAGE_B(1, 1);
    asm volatile("s_waitcnt vmcnt(6)" ::: "memory");
    __builtin_amdgcn_s_barrier();

    int bcur = 0, bnxt = 2;
    #pragma unroll 1
    for (int t = 0; t < NK; ++t) {
        const bool pf = (t + 2 < NK);
        bf16x8 bgf[2], buf2[2];

        // ---- phase 0: B frags + A-hi m0-3 ; stage A-hi(t+2) ----
        {
            #pragma unroll
            for (int nf = 0; nf < 2; ++nf) {
                bgf[nf]  = *reinterpret_cast<const bf16x8*>(&Gs[bcur][rbOff[nf]]);
                buf2[nf] = *reinterpret_cast<const bf16x8*>(&Us[bcur][rbOff[nf]]);
            }
            bf16x8 af[4];
            #pragma unroll
            for (int mf = 0; mf < 4; ++mf)
                af[mf] = *reinterpret_cast<const bf16x8*>(&AsH[bcur][raOff[mf]]);
            if (pf) STAGE_AH(t + 2, bnxt);
            GU_PHASE_SYNC();
            __builtin_amdgcn_s_setprio(1);
            GU_MFMA4(0, af);
            __builtin_amdgcn_s_setprio(0);
            __builtin_amdgcn_s_barrier();
        }
        // ---- phase 1: A-hi m4-7 ; stage A-lo(t+2) ----
        {
            bf16x8 af[4];
            #pragma unroll
            for (int mf = 0; mf < 4; ++mf)
                af[mf] = *reinterpret_cast<const bf16x8*>(&AsH[bcur][raOff[mf + 4]]);
            if (pf) STAGE_AL(t + 2, bnxt);
            GU_PHASE_SYNC();
            __builtin_amdgcn_s_setprio(1);
            GU_MFMA4(4, af);
            __builtin_amdgcn_s_setprio(0);
            __builtin_amdgcn_s_barrier();
        }
        // ---- phase 2: A-lo m0-3 ; stage B(t+2) ----
        {
            bf16x8 af[4];
            #pragma unroll
            for (int mf = 0; mf < 4; ++mf)
                af[mf] = *reinterpret_cast<const bf16x8*>(&AsL[bcur][raOff[mf]]);
            if (pf) STAGE_B(t + 2, bnxt);
            GU_PHASE_SYNC();
            __builtin_amdgcn_s_setprio(1);
            GU_MFMA4(0, af);
            __builtin_amdgcn_s_setprio(0);
            __builtin_amdgcn_s_barrier();
        }
        // ---- phase 3: A-lo m4-7 ; counted vmcnt, never 0 until the tail ----
        {
            bf16x8 af[4];
            #pragma unroll
            for (int mf = 0; mf < 4; ++mf)
                af[mf] = *reinterpret_cast<const bf16x8*>(&AsL[bcur][raOff[mf + 4]]);
            GU_PHASE_SYNC();
            __builtin_amdgcn_s_setprio(1);
            GU_MFMA4(4, af);
            __builtin_amdgcn_s_setprio(0);
            if (t + 2 < NK) {
                asm volatile("s_waitcnt vmcnt(6)" ::: "memory");
            } else if (t + 1 < NK) {
                asm volatile("s_waitcnt vmcnt(0)" ::: "memory");
            }
            __builtin_amdgcn_s_barrier();
        }

        bcur = (bcur == 2) ? 0 : bcur + 1;
        bnxt = (bnxt == 2) ? 0 : bnxt + 1;
    }
#undef STAGE_AH
#undef STAGE_AL
#undef STAGE_B

    // ---- epilogue: silu(g)*u -> bf16 ----
    const int cr = quad * 4;
    #pragma unroll
    for (int mf = 0; mf < 8; ++mf)
        #pragma unroll
        for (int nf = 0; nf < 2; ++nf)
            #pragma unroll
            for (int r = 0; r < 4; ++r) {
                const int gm = m0 + wave_m * 128 + mf * 16 + cr + r;
                const int gn = n0 + wave_n * 32 + nf * 16 + fm;
                const float g = accg[mf][nf][r];
                const float ff = (g / (1.0f + __expf(-g))) * accu[mf][nf][r];
                FF[(size_t)gm * Ff + gn] = f2bf(ff);
            }
}

// ---------------------------------------------------------------------------
// MFMA flash attention — r16 paired-window 8-wave blocks, heavy-first order
// (the 487us-measured config; r17's CU-balanced mapping was null). Windows
// 2p and 2p+1 of the same (b,g) share one block's K/V staging; per-wave work
// bit-identical to r8.
// ---------------------------------------------------------------------------
__global__ __launch_bounds__(512) void attn_mfma_kernel(
    const u16* __restrict__ Qh, const u16* __restrict__ Ql,
    const u16* __restrict__ Kh, const u16* __restrict__ Kl,
    const u16* __restrict__ Vth, const u16* __restrict__ Vtl,
    u16* __restrict__ AOh, u16* __restrict__ AOl)
{
    __shared__ u16 KsH[64 * 72];
    __shared__ u16 KsL[64 * 72];
    __shared__ u16 VsH[64 * 72];
    __shared__ u16 VsL[64 * 72];
    __shared__ u16 Ps[8][16 * 72];     // total LDS 55.3 KB -> 2 blocks/CU

    const int tid = threadIdx.x;
    const int wave = tid >> 6, lane = tid & 63;
    const int l15 = lane & 15, quad = lane >> 4;

    const int bg = blockIdx.x & 7;
    const int b = bg >> 2, g = bg & 3;
    const int pair = 63 - (blockIdx.x >> 3);       // heavy pairs first
    const int win = pair * 2 + (wave >> 2);        // this wave's window
    const int t0 = win * 16;
    const int h = g * 4 + (wave & 3);

    bf16x8 qh[2], ql[2];
    {
        const size_t qrow = (size_t)(b * Tseq + t0 + l15) * 1024 + h * 64;
        #pragma unroll
        for (int ks = 0; ks < 2; ++ks) {
            qh[ks] = *reinterpret_cast<const bf16x8*>(&Qh[qrow + ks * 32 + quad * 8]);
            ql[ks] = *reinterpret_cast<const bf16x8*>(&Ql[qrow + ks * 32 + quad * 8]);
        }
    }

    // staging: 512 threads, 1 uint4 per array each. srow 0..63, scol 0..56.
    const int srow = tid >> 3;
    const int scol = (tid & 7) * 8;
    const size_t kgb = (size_t)(b * Tseq) * 256 + g * 64 + scol;
    const size_t vgb = (size_t)(bg * 64 + srow) * Tseq + scol;

    // shared iteration count for the pair (identical for both windows)
    const int nit = (pair * 32 + 16) / 64 + 1;

    uint4 ck0, cl0, cv0, cw0;
    {
        const size_t ka = kgb + (size_t)srow * 256;
        ck0 = *reinterpret_cast<const uint4*>(&Kh[ka]);
        cl0 = *reinterpret_cast<const uint4*>(&Kl[ka]);
        cv0 = *reinterpret_cast<const uint4*>(&Vth[vgb]);
        cw0 = *reinterpret_cast<const uint4*>(&Vtl[vgb]);
    }

    f32x4 oacc[4];
    #pragma unroll
    for (int nt = 0; nt < 4; ++nt) oacc[nt] = (f32x4){0.f, 0.f, 0.f, 0.f};
    float m_r[4], l_r[4];
    #pragma unroll
    for (int r = 0; r < 4; ++r) { m_r[r] = -1e30f; l_r[r] = 0.0f; }

    u16* psw = &Ps[wave][0];
    const int lb = srow * 72 + scol;

    for (int it = 0; it < nit; ++it) {
        const int s0 = it * 64;
        const bool diag = (it == nit - 1);

        __syncthreads();
        *reinterpret_cast<uint4*>(&KsH[lb]) = ck0;
        *reinterpret_cast<uint4*>(&KsL[lb]) = cl0;
        *reinterpret_cast<uint4*>(&VsH[lb]) = cv0;
        *reinterpret_cast<uint4*>(&VsL[lb]) = cw0;
        if (it + 1 < nit) {
            const size_t ka = kgb + (size_t)(s0 + 64 + srow) * 256;
            ck0 = *reinterpret_cast<const uint4*>(&Kh[ka]);
            cl0 = *reinterpret_cast<const uint4*>(&Kl[ka]);
            const size_t va = vgb + s0 + 64;
            cv0 = *reinterpret_cast<const uint4*>(&Vth[va]);
            cw0 = *reinterpret_cast<const uint4*>(&Vtl[va]);
        }
        __syncthreads();

        f32x4 sacc[4];
        #pragma unroll
        for (int nt = 0; nt < 4; ++nt) sacc[nt] = (f32x4){0.f, 0.f, 0.f, 0.f};

        #pragma unroll
        for (int ks = 0; ks < 2; ++ks) {
            bf16x8 kfh[4], kfl[4];
            #pragma unroll
            for (int nt = 0; nt < 4; ++nt) {
                const int a = (nt * 16 + l15) * 72 + ks * 32 + quad * 8;
                kfh[nt] = *reinterpret_cast<const bf16x8*>(&KsH[a]);
                kfl[nt] = *reinterpret_cast<const bf16x8*>(&KsL[a]);
            }
            #pragma unroll
            for (int nt = 0; nt < 4; ++nt) {
                sacc[nt] = __builtin_amdgcn_mfma_f32_16x16x32_bf16(qh[ks], kfh[nt], sacc[nt], 0, 0, 0);
                sacc[nt] = __builtin_amdgcn_mfma_f32_16x16x32_bf16(ql[ks], kfh[nt], sacc[nt], 0, 0, 0);
                sacc[nt] = __builtin_amdgcn_mfma_f32_16x16x32_bf16(qh[ks], kfl[nt], sacc[nt], 0, 0, 0);
            }
        }

        if (diag) {
            #pragma unroll
            for (int nt = 0; nt < 4; ++nt) {
                const int sg = s0 + nt * 16 + l15;
                #pragma unroll
                for (int r = 0; r < 4; ++r)
                    if (sg > t0 + quad * 4 + r) sacc[nt][r] = -1e30f;
            }
        }

        #pragma unroll
        for (int r = 0; r < 4; ++r) {
            float mx = fmaxf(fmaxf(sacc[0][r], sacc[1][r]),
                             fmaxf(sacc[2][r], sacc[3][r]));
            #pragma unroll
            for (int off = 1; off < 16; off <<= 1)
                mx = fmaxf(mx, __shfl_xor(mx, off, 16));
            const float mnew = fmaxf(m_r[r], mx);
            const float alpha = __expf(m_r[r] - mnew);
            m_r[r] = mnew;

            float rs = 0.0f;
            #pragma unroll
            for (int nt = 0; nt < 4; ++nt) {
                const float p = __expf(sacc[nt][r] - mnew);
                sacc[nt][r] = p;
                rs += p;
            }
            #pragma unroll
            for (int off = 1; off < 16; off <<= 1)
                rs += __shfl_xor(rs, off, 16);
            l_r[r] = l_r[r] * alpha + rs;
            #pragma unroll
            for (int nt = 0; nt < 4; ++nt) oacc[nt][r] *= alpha;
            #pragma unroll
            for (int nt = 0; nt < 4; ++nt)
                psw[(quad * 4 + r) * 72 + nt * 16 + l15] = f2bf(sacc[nt][r]);
        }

        #pragma unroll
        for (int ks = 0; ks < 2; ++ks) {
            const bf16x8 pa = *reinterpret_cast<const bf16x8*>(
                &psw[l15 * 72 + ks * 32 + quad * 8]);
            bf16x8 vfh[4], vfl[4];
            #pragma unroll
            for (int nt = 0; nt < 4; ++nt) {
                const int a = (nt * 16 + l15) * 72 + ks * 32 + quad * 8;
                vfh[nt] = *reinterpret_cast<const bf16x8*>(&VsH[a]);
                vfl[nt] = *reinterpret_cast<const bf16x8*>(&VsL[a]);
            }
            #pragma unroll
            for (int nt = 0; nt < 4; ++nt) {
                oacc[nt] = __builtin_amdgcn_mfma_f32_16x16x32_bf16(pa, vfh[nt], oacc[nt], 0, 0, 0);
                oacc[nt] = __builtin_amdgcn_mfma_f32_16x16x32_bf16(pa, vfl[nt], oacc[nt], 0, 0, 0);
            }
        }
    }

    #pragma unroll
    for (int r = 0; r < 4; ++r) {
        const float inv = 1.0f / l_r[r];
        const size_t orow = (size_t)(b * Tseq + t0 + quad * 4 + r) * 1024 + h * 64;
        #pragma unroll
        for (int nt = 0; nt < 4; ++nt) {
            const float o = oacc[nt][r] * inv;
            const u16 hi = f2bf(o);
            AOh[orow + nt * 16 + l15] = hi;
            AOl[orow + nt * 16 + l15] = f2bf(o - bf2f(hi));
        }
    }
}

// ---------------------------------------------------------------------------
// Host launcher
// ---------------------------------------------------------------------------
extern "C" void kernel_launch(void* const* d_in, const int* in_sizes, int n_in,
                              void* d_out, int out_size, void* d_ws,
                              size_t ws_size, hipStream_t stream)
{
    const float* hidden = (const float*)d_in[0];
    const float* sinp   = (const float*)d_in[1];
    const float* cosp   = (const float*)d_in[2];
    // d_in[3] = mask — causal, handled analytically
    const float* ln1    = (const float*)d_in[4];
    const float* ln2    = (const float*)d_in[5];
    const float* qn     = (const float*)d_in[6];
    const float* kn     = (const float*)d_in[7];
    const float* q_w    = (const float*)d_in[8];
    const float* k_w    = (const float*)d_in[9];
    const float* v_w    = (const float*)d_in[10];
    const float* o_w    = (const float*)d_in[11];
    const float* gate_w = (const float*)d_in[12];
    const float* up_w   = (const float*)d_in[13];
    const float* down_w = (const float*)d_in[14];
    float* out = (float*)d_out;

    // ---- workspace layout (116.4 MB; capacity >= 120.6 MB proven r8) ----
    char* base = (char*)d_ws;
    u16*   OTh  = (u16*)(base);                //  2 MB
    u16*   OTl  = (u16*)(base + 2097152);      //  2 MB
    u16*   GTh  = (u16*)(base + 4194304);      //  8 MB
    u16*   UTh  = (u16*)(base + 12582912);     //  8 MB
    u16*   DTh  = (u16*)(base + 20971520);     //  8 MB
    u16*   QKVT = (u16*)(base + 29360128);     //  3 MB
    u16*   Xh   = (u16*)(base + 32505856);     //  8 MB
    u16*   Qbh  = (u16*)(base + 40894464);     //  8 MB
    u16*   Qbl  = (u16*)(base + 49283072);     //  8 MB
    u16*   Kbh  = (u16*)(base + 57671680);     //  2 MB
    u16*   Kbl  = (u16*)(base + 59768832);     //  2 MB
    u16*   Vth  = (u16*)(base + 61865984);     //  2 MB
    u16*   Vtl  = (u16*)(base + 63963136);     //  2 MB
    u16*   AOh  = (u16*)(base + 66060288);     //  8 MB
    u16*   AOl  = (u16*)(base + 74448896);     //  8 MB
    u16*   FFh  = (u16*)(base + 82837504);     // 32 MB (end 116,391,936)

    // aliases (lifetime-checked):
    float* H2 = (float*)Qbh;   // 16 MB over Qbh+Qbl (Q dead post-attn)
    u16*   Yh = Kbh;           //  8 MB over Kbh..Vtl (K/V dead post-attn)
    u16*   Yl = AOh;           //  8 MB over AOh (AO dead post-o-proj)

    // 0. all weight prep + fused rmsnorm(ln1) in one launch
    wprep_all_kernel<<<14848 + Mrows, 256, 0, stream>>>(
        q_w, k_w, v_w, o_w, gate_w, up_w, down_w, hidden, ln1,
        QKVT, OTh, OTl, GTh, UTh, DTh, Xh);

    // 1. fused qkv projection + qknorm + rope + split + V-transpose (r14 pipe)
    qkv_fused_kernel<<<dim3(12, 32), 256, 0, stream>>>(
        Xh, QKVT, qn, kn, sinp, cosp, Qbh, Qbl, Kbh, Kbl, Vth, Vtl);

    // 2. MFMA flash attention — r16 paired-window blocks, heavy-first (512)
    attn_mfma_kernel<<<Bsz * Gg * (Tseq / 32), 512, 0, stream>>>(
        Qbh, Qbl, Kbh, Kbl, Vth, Vtl, AOh, AOl);

    // 3. hidden2 = hidden + attn @ o_w  (split x split) — BN=128 (r13-exact)
    mfma_gemm_pipe<32, 128, 1, 1, 1><<<dim3(8, 32), 256, 0, stream>>>(
        AOh, AOl, OTh, OTl, hidden, H2, Mrows, Dmod);

    // 4. y = rmsnorm(hidden2, ln2) -> bf16 hi/lo
    rmsnorm_split_kernel<1><<<Mrows, 256, 0, stream>>>(H2, ln2, Yh, Yl);

    // 5. ff = silu(y@gate_w) * (y@up_w) -> FF bf16 (r10/r13-exact)
    gateup8_kernel<<<512, 512, 0, stream>>>(Yh, Yl, GTh, UTh, FFh);

    // 6. out = hidden2 + ff @ down_w — BN=128 (r13-exact)
    mfma_gemm_pipe<128, 128, 0, 0, 1><<<dim3(8, 32), 256, 0, stream>>>(
        FFh, nullptr, DTh, nullptr, H2, out, Mrows, Dmod);
}

// Round 10
// 475.585 us; speedup vs baseline: 1.0672x; 1.0334x over previous
//
#include <hip/hip_runtime.h>
#include <hip/hip_bf16.h>

// Problem constants: B=2, T=2048, D=1024, H=16, G=4, K=64, F=4096
#define EPSF 1e-6f
constexpr int Bsz  = 2;
constexpr int Tseq = 2048;
constexpr int Dmod = 1024;
constexpr int Hh   = 16;
constexpr int Gg   = 4;
constexpr int Ff   = 4096;
constexpr int Mrows = Bsz * Tseq;          // 4096 tokens

typedef __attribute__((ext_vector_type(8))) short bf16x8;   // 8 bf16 (4 VGPRs)
typedef __attribute__((ext_vector_type(4))) float f32x4;
typedef unsigned short u16;

// RNE fp32 -> bf16 (bit pattern as u16)
__device__ inline u16 f2bf(float x) {
    union { float f; unsigned u; } v; v.f = x;
    unsigned r = v.u + 0x7fff + ((v.u >> 16) & 1);
    return (u16)(r >> 16);
}
__device__ inline float bf2f(u16 h) {
    union { unsigned u; float f; } v; v.u = ((unsigned)h) << 16; return v.f;
}

// Async global->LDS DMA, 16 B per lane (wave-uniform base + lane*16).
__device__ __forceinline__ void async_copy16(const u16* g, u16* l) {
    __builtin_amdgcn_global_load_lds(
        (const __attribute__((address_space(1))) void*)g,
        (__attribute__((address_space(3))) void*)l, 16, 0, 0);
}

// Bank-swizzle: LDS tiles [row][32] bf16 (64 B rows). Logical k-chunk q of row
// R stored at chunk q ^ ((R>>1)&3); staging fetches global chunk
// (lane&3)^((row>>1)&3) into linear dest lane*16; reads XOR the same term.
// Conflict-free ONLY for the 16x16 read geometry — verified r7/r10 (=0).
//
// r19 structural change: SINGLE barrier per K-step. The triple-buffer
// invariants need only (a) every wave's vmcnt gate BEFORE the boundary
// barrier (stage(t) complete before any wave reads buffer t), and (b) the
// boundary barrier itself (old reads of bnxt done before restaging). The
// former per-phase barriers + lgkmcnt(0) fences were over-synchronization
// AND compiler pins; removing them lets hipcc software-pipeline ds_reads
// under MFMA (its default strength, m97). Measured basis: gateup matrix-pipe
// busy ~51% (131us, 4875cyc/K-step vs 2480cyc MFMA floor) — the other 49%
// was the 8-barrier lockstep skeleton.
// MFMA order per accumulator unchanged -> bitwise-identical output.

// ---------------------------------------------------------------------------
// ALL weight prep in ONE launch + FUSED rmsnorm(ln1) blocks appended.
// ---------------------------------------------------------------------------
__global__ __launch_bounds__(256) void wprep_all_kernel(
    const float* __restrict__ q_w, const float* __restrict__ k_w,
    const float* __restrict__ v_w, const float* __restrict__ o_w,
    const float* __restrict__ gate_w, const float* __restrict__ up_w,
    const float* __restrict__ down_w,
    const float* __restrict__ hidden, const float* __restrict__ ln1,
    u16* __restrict__ QKVT, u16* __restrict__ OTh, u16* __restrict__ OTl,
    u16* __restrict__ GTh, u16* __restrict__ UTh, u16* __restrict__ DTh,
    u16* __restrict__ Xh)
{
    const int bx = blockIdx.x;

    if (bx >= 14848) {
        // ---- fused rmsnorm(hidden, ln1) -> Xh, one block per token ----
        const int row = bx - 14848;
        const int tid = threadIdx.x;
        const float4 v = reinterpret_cast<const float4*>(hidden + (size_t)row * Dmod)[tid];
        float ss = v.x * v.x + v.y * v.y + v.z * v.z + v.w * v.w;
        #pragma unroll
        for (int off = 32; off; off >>= 1) ss += __shfl_xor(ss, off, 64);
        __shared__ float part[4];
        if ((tid & 63) == 0) part[tid >> 6] = ss;
        __syncthreads();
        const float tot = part[0] + part[1] + part[2] + part[3];
        const float rstd = rsqrtf(tot * (1.0f / Dmod) + EPSF);
        const float4 sc = reinterpret_cast<const float4*>(ln1)[tid];
        ushort4 h;
        h.x = f2bf(v.x * rstd * sc.x); h.y = f2bf(v.y * rstd * sc.y);
        h.z = f2bf(v.z * rstd * sc.z); h.w = f2bf(v.w * rstd * sc.w);
        *reinterpret_cast<ushort4*>(&Xh[(size_t)row * Dmod + tid * 4]) = h;
        return;
    }

    const float* W; u16* Th; u16* Tl = nullptr;
    int N, Kd, ntile, ktile, drow;
    if (bx < 1024) {
        W = q_w; N = 1024; Kd = 1024; ntile = bx & 31; ktile = bx >> 5;
        Th = QKVT; drow = ntile * 32;
    } else if (bx < 1280) {
        const int i = bx - 1024;
        W = k_w; N = 256; Kd = 1024; ntile = i & 7; ktile = i >> 3;
        Th = QKVT; drow = 1024 + ntile * 32;
    } else if (bx < 1536) {
        const int i = bx - 1280;
        W = v_w; N = 256; Kd = 1024; ntile = i & 7; ktile = i >> 3;
        Th = QKVT; drow = 1280 + ntile * 32;
    } else if (bx < 2560) {
        const int i = bx - 1536;
        W = o_w; N = 1024; Kd = 1024; ntile = i & 31; ktile = i >> 5;
        Th = OTh; Tl = OTl; drow = ntile * 32;
    } else if (bx < 6656) {
        const int i = bx - 2560;
        W = gate_w; N = 4096; Kd = 1024; ntile = i & 127; ktile = i >> 7;
        Th = GTh; drow = ntile * 32;
    } else if (bx < 10752) {
        const int i = bx - 6656;
        W = up_w; N = 4096; Kd = 1024; ntile = i & 127; ktile = i >> 7;
        Th = UTh; drow = ntile * 32;
    } else {
        const int i = bx - 10752;
        W = down_w; N = 1024; Kd = 4096; ntile = i & 31; ktile = i >> 5;
        Th = DTh; drow = ntile * 32;
    }
    const int n0 = ntile * 32, k0 = ktile * 32;

    __shared__ float tile[32][33];
    const int r = threadIdx.x >> 3, c4 = (threadIdx.x & 7) * 4;
    const float4 v = *reinterpret_cast<const float4*>(&W[(size_t)(k0 + r) * N + n0 + c4]);
    tile[r][c4 + 0] = v.x; tile[r][c4 + 1] = v.y;
    tile[r][c4 + 2] = v.z; tile[r][c4 + 3] = v.w;
    __syncthreads();
    const int nl = threadIdx.x >> 3, kq = (threadIdx.x & 7) * 4;
    float x0 = tile[kq + 0][nl], x1 = tile[kq + 1][nl];
    float x2 = tile[kq + 2][nl], x3 = tile[kq + 3][nl];
    ushort4 h;
    h.x = f2bf(x0); h.y = f2bf(x1); h.z = f2bf(x2); h.w = f2bf(x3);
    *reinterpret_cast<ushort4*>(&Th[(size_t)(drow + nl) * Kd + k0 + kq]) = h;
    if (Tl) {
        ushort4 l;
        l.x = f2bf(x0 - bf2f(h.x)); l.y = f2bf(x1 - bf2f(h.y));
        l.z = f2bf(x2 - bf2f(h.z)); l.w = f2bf(x3 - bf2f(h.w));
        *reinterpret_cast<ushort4*>(&Tl[(size_t)(drow + nl) * Kd + k0 + kq]) = l;
    }
}

// ---------------------------------------------------------------------------
// RMSNorm over D=1024 -> bf16 hi (+ optional lo). One block per token.
// ---------------------------------------------------------------------------
template <int LO>
__global__ __launch_bounds__(256) void rmsnorm_split_kernel(
    const float* __restrict__ x, const float* __restrict__ scale,
    u16* __restrict__ oh, u16* __restrict__ ol)
{
    const int row = blockIdx.x;
    const int tid = threadIdx.x;
    const float4 v = reinterpret_cast<const float4*>(x + (size_t)row * Dmod)[tid];
    float ss = v.x * v.x + v.y * v.y + v.z * v.z + v.w * v.w;
    #pragma unroll
    for (int off = 32; off; off >>= 1) ss += __shfl_xor(ss, off, 64);
    __shared__ float part[4];
    if ((tid & 63) == 0) part[tid >> 6] = ss;
    __syncthreads();
    const float tot = part[0] + part[1] + part[2] + part[3];
    const float rstd = rsqrtf(tot * (1.0f / Dmod) + EPSF);
    const float4 sc = reinterpret_cast<const float4*>(scale)[tid];
    float o0 = v.x * rstd * sc.x, o1 = v.y * rstd * sc.y;
    float o2 = v.z * rstd * sc.z, o3 = v.w * rstd * sc.w;
    ushort4 h;
    h.x = f2bf(o0); h.y = f2bf(o1); h.z = f2bf(o2); h.w = f2bf(o3);
    *reinterpret_cast<ushort4*>(&oh[(size_t)row * Dmod + tid * 4]) = h;
    if (LO) {
        ushort4 l;
        l.x = f2bf(o0 - bf2f(h.x)); l.y = f2bf(o1 - bf2f(h.y));
        l.z = f2bf(o2 - bf2f(h.z)); l.w = f2bf(o3 - bf2f(h.w));
        *reinterpret_cast<ushort4*>(&ol[(size_t)row * Dmod + tid * 4]) = l;
    }
}

// ---------------------------------------------------------------------------
// Split-bf16 MFMA GEMM, r19: single barrier per K-step (see header note).
// Reads/stages/MFMA order per accumulator unchanged from r13.
// ---------------------------------------------------------------------------
template <int NKT, int BN, int ASPLIT, int BSPLIT, int RES>
__global__ __launch_bounds__(256, 2) void mfma_gemm_pipe(
    const u16* __restrict__ Ah, const u16* __restrict__ Al,
    const u16* __restrict__ Bh, const u16* __restrict__ Bl,
    const float* __restrict__ res, float* __restrict__ C,
    int M, int N)
{
    constexpr int Kd = NKT * 32;
    constexpr int NT = (BN / 2) / 16;                 // n-frags per wave
    constexpr int NI = 2 + 2 * ASPLIT + (BN / 64) + (BN / 64) * BSPLIT;
    static_assert((NKT - 2) % 3 == 0, "main loop unroll-3");

    __shared__ u16 AsH[3][128 * 32];                  // 24 KB
    __shared__ u16 BsH[3][BN * 32];                   // 24/12 KB
    __shared__ u16 AsL[ASPLIT ? 3 : 1][128 * 32];     // 24/8 KB
    __shared__ u16 BsL[BSPLIT ? 3 : 1][BN * 32];      // 24|12 / 8|4 KB

    const int tid = threadIdx.x;
    const int lane = tid & 63, wave = tid >> 6;
    const int wm = (wave >> 1) * 64, wn = (wave & 1) * (BN / 2);
    const int m0 = blockIdx.y * 128, n0 = blockIdx.x * BN;
    const int fm = lane & 15, quad = lane >> 4;
    const int fsw = (fm >> 1) & 3;
    const int fcol = (quad ^ fsw) * 8;

    f32x4 acc[4][NT];
    #pragma unroll
    for (int i = 0; i < 4; ++i)
        #pragma unroll
        for (int j = 0; j < NT; ++j) acc[i][j] = (f32x4){0.f, 0.f, 0.f, 0.f};

    // staging: 256 thr * 16 B = 4 KB/issue; 128x32 tile = 2 issues, 64x32 = 1
    const int srow = tid >> 2;             // 0..63
    const int schk = tid & 3;
    const int sw   = schk ^ ((srow >> 1) & 3);   // f(srow+64)==f(srow)
    const u16* aS0 = &Ah[(size_t)(m0 + srow) * Kd + sw * 8];
    const u16* aS1 = &Ah[(size_t)(m0 + srow + 64) * Kd + sw * 8];
    const u16* bS0 = &Bh[(size_t)(n0 + srow) * Kd + sw * 8];
    const u16* bS1 = (BN == 128) ? &Bh[(size_t)(n0 + srow + 64) * Kd + sw * 8] : nullptr;
    const u16* alS0 = ASPLIT ? &Al[(size_t)(m0 + srow) * Kd + sw * 8] : nullptr;
    const u16* alS1 = ASPLIT ? &Al[(size_t)(m0 + srow + 64) * Kd + sw * 8] : nullptr;
    const u16* blS0 = BSPLIT ? &Bl[(size_t)(n0 + srow) * Kd + sw * 8] : nullptr;
    const u16* blS1 = (BSPLIT && BN == 128) ? &Bl[(size_t)(n0 + srow + 64) * Kd + sw * 8] : nullptr;
    const int dst0 = srow * 32 + schk * 8;       // bytes = tid*16 (linear)
    const int dst1 = dst0 + 64 * 32;

#define PSTAGE(T, BUF) do {                                                  \
        async_copy16(aS0 + (T) * 32, &AsH[BUF][dst0]);                       \
        async_copy16(aS1 + (T) * 32, &AsH[BUF][dst1]);                       \
        if (ASPLIT) {                                                        \
            async_copy16(alS0 + (T) * 32, &AsL[BUF][dst0]);                  \
            async_copy16(alS1 + (T) * 32, &AsL[BUF][dst1]);                  \
        }                                                                    \
        async_copy16(bS0 + (T) * 32, &BsH[BUF][dst0]);                       \
        if (BN == 128) async_copy16(bS1 + (T) * 32, &BsH[BUF][dst1]);        \
        if (BSPLIT) {                                                        \
            async_copy16(blS0 + (T) * 32, &BsL[BUF][dst0]);                  \
            if (BN == 128) async_copy16(blS1 + (T) * 32, &BsL[BUF][dst1]);   \
        }                                                                    \
    } while (0)

// GATE: 1 = steady-state counted wait vmcnt(NI), 0 = drain, -1 = none.
#define PGATE(GATE) do {                                                     \
        if ((GATE) == 1) {                                                   \
            if constexpr (NI == 3)                                           \
                asm volatile("s_waitcnt vmcnt(3)" ::: "memory");             \
            else if constexpr (NI == 4)                                      \
                asm volatile("s_waitcnt vmcnt(4)" ::: "memory");             \
            else if constexpr (NI == 6)                                      \
                asm volatile("s_waitcnt vmcnt(6)" ::: "memory");             \
            else                                                             \
                asm volatile("s_waitcnt vmcnt(8)" ::: "memory");             \
        } else if ((GATE) == 0) {                                            \
            asm volatile("s_waitcnt vmcnt(0)" ::: "memory");                 \
        }                                                                    \
    } while (0)

// r19: single barrier per K-step; no mid-step barrier / lgkmcnt(0) pin —
// compiler orders ds_read->MFMA via its own counted lgkmcnt.
#define PSTEP(BC, BN_, T, PF, GATE) do {                                     \
    bf16x8 ah[4], bh[NT], al[4], bl[NT];                                     \
    _Pragma("unroll")                                                        \
    for (int t = 0; t < 4; ++t) {                                            \
        const int ra = (wm + t * 16 + fm) * 32 + fcol;                       \
        ah[t] = *reinterpret_cast<const bf16x8*>(&AsH[BC][ra]);              \
        if (ASPLIT) al[t] = *reinterpret_cast<const bf16x8*>(&AsL[BC][ra]);  \
    }                                                                        \
    _Pragma("unroll")                                                        \
    for (int t = 0; t < NT; ++t) {                                           \
        const int rb = (wn + t * 16 + fm) * 32 + fcol;                       \
        bh[t] = *reinterpret_cast<const bf16x8*>(&BsH[BC][rb]);              \
        if (BSPLIT) bl[t] = *reinterpret_cast<const bf16x8*>(&BsL[BC][rb]);  \
    }                                                                        \
    if (PF) PSTAGE((T) + 2, BN_);                                            \
    __builtin_amdgcn_s_setprio(1);                                           \
    _Pragma("unroll")                                                        \
    for (int mt = 0; mt < 4; ++mt)                                           \
        _Pragma("unroll")                                                    \
        for (int nt = 0; nt < NT; ++nt) {                                    \
            acc[mt][nt] = __builtin_amdgcn_mfma_f32_16x16x32_bf16(           \
                ah[mt], bh[nt], acc[mt][nt], 0, 0, 0);                       \
            if (BSPLIT)                                                      \
                acc[mt][nt] = __builtin_amdgcn_mfma_f32_16x16x32_bf16(       \
                    ah[mt], bl[nt], acc[mt][nt], 0, 0, 0);                   \
            if (ASPLIT)                                                      \
                acc[mt][nt] = __builtin_amdgcn_mfma_f32_16x16x32_bf16(       \
                    al[mt], bh[nt], acc[mt][nt], 0, 0, 0);                   \
        }                                                                    \
    __builtin_amdgcn_s_setprio(0);                                           \
    PGATE(GATE);                                                             \
    __builtin_amdgcn_s_barrier();                                            \
} while (0)

    // prologue: fill buffers 0 and 1 (2*NI in flight -> wait NI = buf0 done)
    PSTAGE(0, 0);
    PSTAGE(1, 1);
    PGATE(1);
    __builtin_amdgcn_s_barrier();

    #pragma unroll 1
    for (int t3 = 0; t3 < NKT - 2; t3 += 3) {
        PSTEP(0, 2, t3 + 0, true, 1);
        PSTEP(1, 0, t3 + 1, true, 1);
        PSTEP(2, 1, t3 + 2, true, 1);
    }
    // tail: t=NKT-2 (buf0, drain last loads), t=NKT-1 (buf1, nothing left)
    PSTEP(0, 2, NKT - 2, false, 0);
    PSTEP(1, 0, NKT - 1, false, -1);

#undef PSTEP
#undef PGATE
#undef PSTAGE

    const int cr = (lane >> 4) * 4, cn = lane & 15;
    #pragma unroll
    for (int mt = 0; mt < 4; ++mt)
        #pragma unroll
        for (int nt = 0; nt < NT; ++nt)
            #pragma unroll
            for (int r = 0; r < 4; ++r) {
                const int gm = m0 + wm + mt * 16 + cr + r;
                const int gn = n0 + wn + nt * 16 + cn;
                float v = acc[mt][nt][r];
                if (RES) v += res[(size_t)gm * N + gn];
                C[(size_t)gm * N + gn] = v;
            }
}

// ---------------------------------------------------------------------------
// Fused QKV GEMM + qk-norm + RoPE + bf16 split epilogue; V stored TRANSPOSED.
// r19: single barrier per K-step (same invariant argument). Epilogue unchanged.
// ---------------------------------------------------------------------------
__global__ __launch_bounds__(256, 2) void qkv_fused_kernel(
    const u16* __restrict__ Ah, const u16* __restrict__ Bh,
    const float* __restrict__ qn, const float* __restrict__ kn,
    const float* __restrict__ sinp, const float* __restrict__ cosp,
    u16* __restrict__ Qbh, u16* __restrict__ Qbl,
    u16* __restrict__ Kbh, u16* __restrict__ Kbl,
    u16* __restrict__ Vth, u16* __restrict__ Vtl)
{
    constexpr int Kd = 1024;
    constexpr int NKT = 32;
    __shared__ u16 As[3][128 * 32];    // 24 KB
    __shared__ u16 Bs[3][128 * 32];    // 24 KB -> 48 KB total

    const int tid = threadIdx.x;
    const int lane = tid & 63, wave = tid >> 6;
    const int wm = (wave >> 1) * 64, wn = (wave & 1) * 64;
    const int m0 = blockIdx.y * 128, n0 = blockIdx.x * 128;
    const int fm = lane & 15, quad = lane >> 4;
    const int fsw = (fm >> 1) & 3;
    const int fcol = ((quad ^ fsw) * 8);

    f32x4 acc[4][4];
    #pragma unroll
    for (int i = 0; i < 4; ++i)
        #pragma unroll
        for (int j = 0; j < 4; ++j) acc[i][j] = (f32x4){0.f, 0.f, 0.f, 0.f};

    const int srow = tid >> 2;             // 0..63
    const int schk = tid & 3;
    const int sw   = schk ^ ((srow >> 1) & 3);
    const u16* aS0 = &Ah[(size_t)(m0 + srow) * Kd + sw * 8];
    const u16* aS1 = &Ah[(size_t)(m0 + srow + 64) * Kd + sw * 8];
    const u16* bS0 = &Bh[(size_t)(n0 + srow) * Kd + sw * 8];
    const u16* bS1 = &Bh[(size_t)(n0 + srow + 64) * Kd + sw * 8];
    const int dst0 = srow * 32 + schk * 8;
    const int dst1 = dst0 + 64 * 32;

#define QSTAGE(T, BUF) do {                                                  \
        async_copy16(aS0 + (T) * 32, &As[BUF][dst0]);                        \
        async_copy16(aS1 + (T) * 32, &As[BUF][dst1]);                        \
        async_copy16(bS0 + (T) * 32, &Bs[BUF][dst0]);                        \
        async_copy16(bS1 + (T) * 32, &Bs[BUF][dst1]);                        \
    } while (0)

#define QSTEP(BC, BN, T, PF, GATE) do {                                      \
    bf16x8 ah[4], bh[4];                                                     \
    _Pragma("unroll")                                                        \
    for (int t = 0; t < 4; ++t) {                                            \
        ah[t] = *reinterpret_cast<const bf16x8*>(                            \
            &As[BC][(wm + t * 16 + fm) * 32 + fcol]);                        \
        bh[t] = *reinterpret_cast<const bf16x8*>(                            \
            &Bs[BC][(wn + t * 16 + fm) * 32 + fcol]);                        \
    }                                                                        \
    if (PF) QSTAGE((T) + 2, BN);                                             \
    __builtin_amdgcn_s_setprio(1);                                           \
    _Pragma("unroll")                                                        \
    for (int mt = 0; mt < 4; ++mt)                                           \
        _Pragma("unroll")                                                    \
        for (int nt = 0; nt < 4; ++nt)                                       \
            acc[mt][nt] = __builtin_amdgcn_mfma_f32_16x16x32_bf16(           \
                ah[mt], bh[nt], acc[mt][nt], 0, 0, 0);                       \
    __builtin_amdgcn_s_setprio(0);                                           \
    if ((GATE) == 1) {                                                       \
        asm volatile("s_waitcnt vmcnt(4)" ::: "memory");                     \
    } else if ((GATE) == 0) {                                                \
        asm volatile("s_waitcnt vmcnt(0)" ::: "memory");                     \
    }                                                                        \
    __builtin_amdgcn_s_barrier();                                            \
} while (0)

    QSTAGE(0, 0);
    QSTAGE(1, 1);
    asm volatile("s_waitcnt vmcnt(4)" ::: "memory");
    __builtin_amdgcn_s_barrier();

    #pragma unroll 1
    for (int t3 = 0; t3 < NKT - 2; t3 += 3) {
        QSTEP(0, 2, t3 + 0, true, 1);
        QSTEP(1, 0, t3 + 1, true, 1);
        QSTEP(2, 1, t3 + 2, true, 1);
    }
    QSTEP(0, 2, NKT - 2, false, 0);
    QSTEP(1, 0, NKT - 1, false, -1);

#undef QSTEP
#undef QSTAGE

    const int gn0 = n0 + wn;          // wave col base, 64-aligned
    const int l15 = lane & 15;

    if (gn0 < 1280) {
        // ---- Q or K: per-head RMSNorm + RoPE + split ----
        const bool isQ = (gn0 < 1024);
        const float* nsc = isQ ? qn : kn;
        const float osc = isQ ? 0.125f : 1.0f;
        u16* __restrict__ oh = isQ ? Qbh : Kbh;
        u16* __restrict__ ol = isQ ? Qbl : Kbl;
        const int rowstride = isQ ? 1024 : 256;
        const int colbase = isQ ? gn0 : gn0 - 1024;
        float sc[4];
        #pragma unroll
        for (int nt = 0; nt < 4; ++nt) sc[nt] = nsc[nt * 16 + l15];

        #pragma unroll
        for (int mt = 0; mt < 4; ++mt)
            #pragma unroll
            for (int r = 0; r < 4; ++r) {
                const int bt = m0 + wm + mt * 16 + quad * 4 + r;
                float v[4];
                #pragma unroll
                for (int nt = 0; nt < 4; ++nt) v[nt] = acc[mt][nt][r];
                float ss = v[0] * v[0] + v[1] * v[1] + v[2] * v[2] + v[3] * v[3];
                #pragma unroll
                for (int off = 1; off < 16; off <<= 1)
                    ss += __shfl_xor(ss, off, 16);
                const float rstd = rsqrtf(ss * (1.0f / 64.0f) + EPSF);
                float nv[4];
                #pragma unroll
                for (int nt = 0; nt < 4; ++nt) nv[nt] = v[nt] * rstd * sc[nt];
                const float s0 = sinp[bt * 32 + l15];
                const float c0 = cosp[bt * 32 + l15];
                const float s1 = sinp[bt * 32 + 16 + l15];
                const float c1 = cosp[bt * 32 + 16 + l15];
                float o[4];
                o[0] = (nv[0] * c0 - nv[2] * s0) * osc;
                o[1] = (nv[1] * c1 - nv[3] * s1) * osc;
                o[2] = (nv[2] * c0 + nv[0] * s0) * osc;
                o[3] = (nv[3] * c1 + nv[1] * s1) * osc;
                #pragma unroll
                for (int nt = 0; nt < 4; ++nt) {
                    const size_t off = (size_t)bt * rowstride + colbase + nt * 16 + l15;
                    const u16 hi = f2bf(o[nt]);
                    oh[off] = hi;
                    ol[off] = f2bf(o[nt] - bf2f(hi));
                }
            }
    } else {
        // ---- V: bf16 split, stored transposed: Vt[(b*4+g)*64+d][t] ----
        const int g = (gn0 - 1280) >> 6;
        const int b = (m0 + wm) >> 11;
        const int tb = ((m0 + wm) & 2047) + quad * 4;
        #pragma unroll
        for (int mt = 0; mt < 4; ++mt)
            #pragma unroll
            for (int nt = 0; nt < 4; ++nt) {
                const float v0 = acc[mt][nt][0], v1 = acc[mt][nt][1];
                const float v2 = acc[mt][nt][2], v3 = acc[mt][nt][3];
                ushort4 hv, lv;
                hv.x = f2bf(v0); hv.y = f2bf(v1); hv.z = f2bf(v2); hv.w = f2bf(v3);
                lv.x = f2bf(v0 - bf2f(hv.x)); lv.y = f2bf(v1 - bf2f(hv.y));
                lv.z = f2bf(v2 - bf2f(hv.z)); lv.w = f2bf(v3 - bf2f(hv.w));
                const size_t off =
                    ((size_t)((b * 4 + g) * 64 + nt * 16 + l15)) * Tseq + tb + mt * 16;
                *reinterpret_cast<ushort4*>(&Vth[off]) = hv;
                *reinterpret_cast<ushort4*>(&Vtl[off]) = lv;
            }
    }
}

// ---------------------------------------------------------------------------
// Fused gate/up GEMM — r19: r10 data layout + read/stage order, but ONE
// barrier per K-step (was 8). Invariants per header note. MFMA order per
// accumulator unchanged -> bitwise-identical output. Cross-run CLOCK ANCHOR.
// ---------------------------------------------------------------------------
#define GU_MFMA4(MBASE, AF)                                                      \
    _Pragma("unroll")                                                            \
    for (int mf = 0; mf < 4; ++mf) {                                             \
        accg[(MBASE) + mf][0] = __builtin_amdgcn_mfma_f32_16x16x32_bf16(         \
            AF[mf], bgf[0], accg[(MBASE) + mf][0], 0, 0, 0);                     \
        accu[(MBASE) + mf][0] = __builtin_amdgcn_mfma_f32_16x16x32_bf16(         \
            AF[mf], buf2[0], accu[(MBASE) + mf][0], 0, 0, 0);                    \
        accg[(MBASE) + mf][1] = __builtin_amdgcn_mfma_f32_16x16x32_bf16(         \
            AF[mf], bgf[1], accg[(MBASE) + mf][1], 0, 0, 0);                     \
        accu[(MBASE) + mf][1] = __builtin_amdgcn_mfma_f32_16x16x32_bf16(         \
            AF[mf], buf2[1], accu[(MBASE) + mf][1], 0, 0, 0);                    \
    }

__global__ __launch_bounds__(512, 2) void gateup8_kernel(
    const u16* __restrict__ Yh, const u16* __restrict__ Yl,
    const u16* __restrict__ Gw, const u16* __restrict__ Uw,
    u16* __restrict__ FF)
{
    constexpr int NK = 32;                 // K=1024 / 32
    __shared__ u16 AsH[3][256 * 32];       // 48 KB
    __shared__ u16 AsL[3][256 * 32];       // 48 KB
    __shared__ u16 Gs[3][128 * 32];        // 24 KB
    __shared__ u16 Us[3][128 * 32];        // 24 KB  -> 144 KB total, 1 blk/CU

    const int tid  = threadIdx.x;
    const int lane = tid & 63;
    const int wave = tid >> 6;
    const int wave_m = wave >> 2;          // 0..1  -> A rows wave_m*128..+127
    const int wave_n = wave & 3;           // 0..3  -> B rows wave_n*32..+31

    // XCD-aware bijective swizzle: 512 wgs = 8 xcd * 64.
    const int wg  = blockIdx.x;
    const int xcd = wg & 7;
    const int idx = wg >> 3;               // 0..63
    const int ntile = xcd * 4 + (idx & 3); // 0..31
    const int mtile = idx >> 2;            // 0..15
    const int m0 = mtile * 256, n0 = ntile * 128;

    const int fm = lane & 15, quad = lane >> 4;
    const int fsw = (fm >> 1) & 3;
    const int fcol = (quad ^ fsw) * 8;

    f32x4 accg[8][2], accu[8][2];
    #pragma unroll
    for (int i = 0; i < 8; ++i)
        #pragma unroll
        for (int j = 0; j < 2; ++j) {
            accg[i][j] = (f32x4){0.f, 0.f, 0.f, 0.f};
            accu[i][j] = (f32x4){0.f, 0.f, 0.f, 0.f};
        }

    // ---- staging constants (512 thr * 16 B = 8 KB per issue) ----
    const int srow = tid >> 2;             // 0..127
    const int schk = tid & 3;
    const int sw   = schk ^ ((srow >> 1) & 3);   // same for srow+128 (128%4==0)
    const u16* aSrc0 = &Yh[(size_t)(m0 + srow) * 1024 + sw * 8];
    const u16* aSrc1 = &Yh[(size_t)(m0 + srow + 128) * 1024 + sw * 8];
    const u16* lSrc0 = &Yl[(size_t)(m0 + srow) * 1024 + sw * 8];
    const u16* lSrc1 = &Yl[(size_t)(m0 + srow + 128) * 1024 + sw * 8];
    const u16* gSrc  = &Gw[(size_t)(n0 + srow) * 1024 + sw * 8];
    const u16* uSrc  = &Uw[(size_t)(n0 + srow) * 1024 + sw * 8];
    const int aDst0 = srow * 32 + schk * 8;      // bytes = tid*16 (linear)
    const int aDst1 = aDst0 + 128 * 32;

#define STAGE_AH(T, BUF) do {                                  \
        async_copy16(aSrc0 + (T) * 32, &AsH[BUF][aDst0]);      \
        async_copy16(aSrc1 + (T) * 32, &AsH[BUF][aDst1]); } while (0)
#define STAGE_AL(T, BUF) do {                                  \
        async_copy16(lSrc0 + (T) * 32, &AsL[BUF][aDst0]);      \
        async_copy16(lSrc1 + (T) * 32, &AsL[BUF][aDst1]); } while (0)
#define STAGE_B(T, BUF) do {                                   \
        async_copy16(gSrc + (T) * 32, &Gs[BUF][aDst0]);        \
        async_copy16(uSrc + (T) * 32, &Us[BUF][aDst0]); } while (0)

    // ---- fragment read offsets (u16 units) ----
    int raOff[8], rbOff[2];
    #pragma unroll
    for (int mf = 0; mf < 8; ++mf)
        raOff[mf] = (wave_m * 128 + mf * 16 + fm) * 32 + fcol;
    #pragma unroll
    for (int nf = 0; nf < 2; ++nf)
        rbOff[nf] = (wave_n * 32 + nf * 16 + fm) * 32 + fcol;

    // ---- prologue: fill buffers 0 and 1 (12 loads in flight -> wait 6) ----
    STAGE_AH(0, 0); STAGE_AL(0, 0); STAGE_B(0, 0);
    STAGE_AH(1, 1); STAGE_AL(1, 1); STAGE_B(1, 1);
    asm volatile("s_waitcnt vmcnt(6)" ::: "memory");
    __builtin_amdgcn_s_barrier();

// One K-step, r19: 4 MFMA clusters with interleaved reads/stages, NO intra
// barriers; single vmcnt-gate + barrier at the boundary. Compiler pipelines
// ds_reads under MFMA via its own counted lgkmcnt.
#define GU_STEP(BC, BN_, T, PF, GATE) do {                                   \
    bf16x8 bgf[2], buf2[2];                                                  \
    _Pragma("unroll")                                                        \
    for (int nf = 0; nf < 2; ++nf) {                                         \
        bgf[nf]  = *reinterpret_cast<const bf16x8*>(&Gs[BC][rbOff[nf]]);     \
        buf2[nf] = *reinterpret_cast<const bf16x8*>(&Us[BC][rbOff[nf]]);     \
    }                                                                        \
    {                                                                        \
        bf16x8 af[4];                                                        \
        _Pragma("unroll")                                                    \
        for (int mf = 0; mf < 4; ++mf)                                       \
            af[mf] = *reinterpret_cast<const bf16x8*>(&AsH[BC][raOff[mf]]);  \
        if (PF) STAGE_AH((T) + 2, BN_);                                      \
        __builtin_amdgcn_s_setprio(1);                                       \
        GU_MFMA4(0, af);                                                     \
        __builtin_amdgcn_s_setprio(0);                                       \
    }                                                                        \
    {                                                                        \
        bf16x8 af[4];                                                        \
        _Pragma("unroll")                                                    \
        for (int mf = 0; mf < 4; ++mf)                                       \
            af[mf] = *reinterpret_cast<const bf16x8*>(&AsH[BC][raOff[mf + 4]]); \
        if (PF) STAGE_AL((T) + 2, BN_);                                      \
        __builtin_amdgcn_s_setprio(1);                                       \
        GU_MFMA4(4, af);                                                     \
        __builtin_amdgcn_s_setprio(0);                                       \
    }                                                                        \
    {                                                                        \
        bf16x8 af[4];                                                        \
        _Pragma("unroll")                                                    \
        for (int mf = 0; mf < 4; ++mf)                                       \
            af[mf] = *reinterpret_cast<const bf16x8*>(&AsL[BC][raOff[mf]]);  \
        if (PF) STAGE_B((T) + 2, BN_);                                       \
        __builtin_amdgcn_s_setprio(1);                                       \
        GU_MFMA4(0, af);                                                     \
        __builtin_amdgcn_s_setprio(0);                                       \
    }                                                                        \
    {                                                                        \
        bf16x8 af[4];                                                        \
        _Pragma("unroll")                                                    \
        for (int mf = 0; mf < 4; ++mf)                                       \
            af[mf] = *reinterpret_cast<const bf16x8*>(&AsL[BC][raOff[mf + 4]]); \
        __builtin_amdgcn_s_setprio(1);                                       \
        GU_MFMA4(4, af);                                                     \
        __builtin_amdgcn_s_setprio(0);                                       \
    }                                                                        \
    if ((GATE) == 1) {                                                       \
        asm volatile("s_waitcnt vmcnt(6)" ::: "memory");                     \
    } else if ((GATE) == 0) {                                                \
        asm volatile("s_waitcnt vmcnt(0)" ::: "memory");                     \
    }                                                                        \
    __builtin_amdgcn_s_barrier();                                            \
} while (0)

    #pragma unroll 1
    for (int t3 = 0; t3 < NK - 2; t3 += 3) {
        GU_STEP(0, 2, t3 + 0, true, 1);
        GU_STEP(1, 0, t3 + 1, true, 1);
        GU_STEP(2, 1, t3 + 2, true, 1);
    }
    GU_STEP(0, 2, 30, false, 0);
    GU_STEP(1, 0, 31, false, -1);

#undef GU_STEP
#undef STAGE_AH
#undef STAGE_AL
#undef STAGE_B

    // ---- epilogue: silu(g)*u -> bf16 ----
    const int cr = quad * 4;
    #pragma unroll
    for (int mf = 0; mf < 8; ++mf)
        #pragma unroll
        for (int nf = 0; nf < 2; ++nf)
            #pragma unroll
            for (int r = 0; r < 4; ++r) {
                const int gm = m0 + wave_m * 128 + mf * 16 + cr + r;
                const int gn = n0 + wave_n * 32 + nf * 16 + fm;
                const float g = accg[mf][nf][r];
                const float ff = (g / (1.0f + __expf(-g))) * accu[mf][nf][r];
                FF[(size_t)gm * Ff + gn] = f2bf(ff);
            }
}

// ---------------------------------------------------------------------------
// MFMA flash attention — r16 paired-window 8-wave blocks, heavy-first order.
// ---------------------------------------------------------------------------
__global__ __launch_bounds__(512) void attn_mfma_kernel(
    const u16* __restrict__ Qh, const u16* __restrict__ Ql,
    const u16* __restrict__ Kh, const u16* __restrict__ Kl,
    const u16* __restrict__ Vth, const u16* __restrict__ Vtl,
    u16* __restrict__ AOh, u16* __restrict__ AOl)
{
    __shared__ u16 KsH[64 * 72];
    __shared__ u16 KsL[64 * 72];
    __shared__ u16 VsH[64 * 72];
    __shared__ u16 VsL[64 * 72];
    __shared__ u16 Ps[8][16 * 72];     // total LDS 55.3 KB -> 2 blocks/CU

    const int tid = threadIdx.x;
    const int wave = tid >> 6, lane = tid & 63;
    const int l15 = lane & 15, quad = lane >> 4;

    const int bg = blockIdx.x & 7;
    const int b = bg >> 2, g = bg & 3;
    const int pair = 63 - (blockIdx.x >> 3);       // heavy pairs first
    const int win = pair * 2 + (wave >> 2);        // this wave's window
    const int t0 = win * 16;
    const int h = g * 4 + (wave & 3);

    bf16x8 qh[2], ql[2];
    {
        const size_t qrow = (size_t)(b * Tseq + t0 + l15) * 1024 + h * 64;
        #pragma unroll
        for (int ks = 0; ks < 2; ++ks) {
            qh[ks] = *reinterpret_cast<const bf16x8*>(&Qh[qrow + ks * 32 + quad * 8]);
            ql[ks] = *reinterpret_cast<const bf16x8*>(&Ql[qrow + ks * 32 + quad * 8]);
        }
    }

    // staging: 512 threads, 1 uint4 per array each. srow 0..63, scol 0..56.
    const int srow = tid >> 3;
    const int scol = (tid & 7) * 8;
    const size_t kgb = (size_t)(b * Tseq) * 256 + g * 64 + scol;
    const size_t vgb = (size_t)(bg * 64 + srow) * Tseq + scol;

    // shared iteration count for the pair (identical for both windows)
    const int nit = (pair * 32 + 16) / 64 + 1;

    uint4 ck0, cl0, cv0, cw0;
    {
        const size_t ka = kgb + (size_t)srow * 256;
        ck0 = *reinterpret_cast<const uint4*>(&Kh[ka]);
        cl0 = *reinterpret_cast<const uint4*>(&Kl[ka]);
        cv0 = *reinterpret_cast<const uint4*>(&Vth[vgb]);
        cw0 = *reinterpret_cast<const uint4*>(&Vtl[vgb]);
    }

    f32x4 oacc[4];
    #pragma unroll
    for (int nt = 0; nt < 4; ++nt) oacc[nt] = (f32x4){0.f, 0.f, 0.f, 0.f};
    float m_r[4], l_r[4];
    #pragma unroll
    for (int r = 0; r < 4; ++r) { m_r[r] = -1e30f; l_r[r] = 0.0f; }

    u16* psw = &Ps[wave][0];
    const int lb = srow * 72 + scol;

    for (int it = 0; it < nit; ++it) {
        const int s0 = it * 64;
        const bool diag = (it == nit - 1);

        __syncthreads();
        *reinterpret_cast<uint4*>(&KsH[lb]) = ck0;
        *reinterpret_cast<uint4*>(&KsL[lb]) = cl0;
        *reinterpret_cast<uint4*>(&VsH[lb]) = cv0;
        *reinterpret_cast<uint4*>(&VsL[lb]) = cw0;
        if (it + 1 < nit) {
            const size_t ka = kgb + (size_t)(s0 + 64 + srow) * 256;
            ck0 = *reinterpret_cast<const uint4*>(&Kh[ka]);
            cl0 = *reinterpret_cast<const uint4*>(&Kl[ka]);
            const size_t va = vgb + s0 + 64;
            cv0 = *reinterpret_cast<const uint4*>(&Vth[va]);
            cw0 = *reinterpret_cast<const uint4*>(&Vtl[va]);
        }
        __syncthreads();

        f32x4 sacc[4];
        #pragma unroll
        for (int nt = 0; nt < 4; ++nt) sacc[nt] = (f32x4){0.f, 0.f, 0.f, 0.f};

        #pragma unroll
        for (int ks = 0; ks < 2; ++ks) {
            bf16x8 kfh[4], kfl[4];
            #pragma unroll
            for (int nt = 0; nt < 4; ++nt) {
                const int a = (nt * 16 + l15) * 72 + ks * 32 + quad * 8;
                kfh[nt] = *reinterpret_cast<const bf16x8*>(&KsH[a]);
                kfl[nt] = *reinterpret_cast<const bf16x8*>(&KsL[a]);
            }
            #pragma unroll
            for (int nt = 0; nt < 4; ++nt) {
                sacc[nt] = __builtin_amdgcn_mfma_f32_16x16x32_bf16(qh[ks], kfh[nt], sacc[nt], 0, 0, 0);
                sacc[nt] = __builtin_amdgcn_mfma_f32_16x16x32_bf16(ql[ks], kfh[nt], sacc[nt], 0, 0, 0);
                sacc[nt] = __builtin_amdgcn_mfma_f32_16x16x32_bf16(qh[ks], kfl[nt], sacc[nt], 0, 0, 0);
            }
        }

        if (diag) {
            #pragma unroll
            for (int nt = 0; nt < 4; ++nt) {
                const int sg = s0 + nt * 16 + l15;
                #pragma unroll
                for (int r = 0; r < 4; ++r)
                    if (sg > t0 + quad * 4 + r) sacc[nt][r] = -1e30f;
            }
        }

        #pragma unroll
        for (int r = 0; r < 4; ++r) {
            float mx = fmaxf(fmaxf(sacc[0][r], sacc[1][r]),
                             fmaxf(sacc[2][r], sacc[3][r]));
            #pragma unroll
            for (int off = 1; off < 16; off <<= 1)
                mx = fmaxf(mx, __shfl_xor(mx, off, 16));
            const float mnew = fmaxf(m_r[r], mx);
            const float alpha = __expf(m_r[r] - mnew);
            m_r[r] = mnew;

            float rs = 0.0f;
            #pragma unroll
            for (int nt = 0; nt < 4; ++nt) {
                const float p = __expf(sacc[nt][r] - mnew);
                sacc[nt][r] = p;
                rs += p;
            }
            #pragma unroll
            for (int off = 1; off < 16; off <<= 1)
                rs += __shfl_xor(rs, off, 16);
            l_r[r] = l_r[r] * alpha + rs;
            #pragma unroll
            for (int nt = 0; nt < 4; ++nt) oacc[nt][r] *= alpha;
            #pragma unroll
            for (int nt = 0; nt < 4; ++nt)
                psw[(quad * 4 + r) * 72 + nt * 16 + l15] = f2bf(sacc[nt][r]);
        }

        #pragma unroll
        for (int ks = 0; ks < 2; ++ks) {
            const bf16x8 pa = *reinterpret_cast<const bf16x8*>(
                &psw[l15 * 72 + ks * 32 + quad * 8]);
            bf16x8 vfh[4], vfl[4];
            #pragma unroll
            for (int nt = 0; nt < 4; ++nt) {
                const int a = (nt * 16 + l15) * 72 + ks * 32 + quad * 8;
                vfh[nt] = *reinterpret_cast<const bf16x8*>(&VsH[a]);
                vfl[nt] = *reinterpret_cast<const bf16x8*>(&VsL[a]);
            }
            #pragma unroll
            for (int nt = 0; nt < 4; ++nt) {
                oacc[nt] = __builtin_amdgcn_mfma_f32_16x16x32_bf16(pa, vfh[nt], oacc[nt], 0, 0, 0);
                oacc[nt] = __builtin_amdgcn_mfma_f32_16x16x32_bf16(pa, vfl[nt], oacc[nt], 0, 0, 0);
            }
        }
    }

    #pragma unroll
    for (int r = 0; r < 4; ++r) {
        const float inv = 1.0f / l_r[r];
        const size_t orow = (size_t)(b * Tseq + t0 + quad * 4 + r) * 1024 + h * 64;
        #pragma unroll
        for (int nt = 0; nt < 4; ++nt) {
            const float o = oacc[nt][r] * inv;
            const u16 hi = f2bf(o);
            AOh[orow + nt * 16 + l15] = hi;
            AOl[orow + nt * 16 + l15] = f2bf(o - bf2f(hi));
        }
    }
}

// ---------------------------------------------------------------------------
// Host launcher
// ---------------------------------------------------------------------------
extern "C" void kernel_launch(void* const* d_in, const int* in_sizes, int n_in,
                              void* d_out, int out_size, void* d_ws,
                              size_t ws_size, hipStream_t stream)
{
    const float* hidden = (const float*)d_in[0];
    const float* sinp   = (const float*)d_in[1];
    const float* cosp   = (const float*)d_in[2];
    // d_in[3] = mask — causal, handled analytically
    const float* ln1    = (const float*)d_in[4];
    const float* ln2    = (const float*)d_in[5];
    const float* qn     = (const float*)d_in[6];
    const float* kn     = (const float*)d_in[7];
    const float* q_w    = (const float*)d_in[8];
    const float* k_w    = (const float*)d_in[9];
    const float* v_w    = (const float*)d_in[10];
    const float* o_w    = (const float*)d_in[11];
    const float* gate_w = (const float*)d_in[12];
    const float* up_w   = (const float*)d_in[13];
    const float* down_w = (const float*)d_in[14];
    float* out = (float*)d_out;

    // ---- workspace layout (116.4 MB; capacity >= 120.6 MB proven r8) ----
    char* base = (char*)d_ws;
    u16*   OTh  = (u16*)(base);                //  2 MB
    u16*   OTl  = (u16*)(base + 2097152);      //  2 MB
    u16*   GTh  = (u16*)(base + 4194304);      //  8 MB
    u16*   UTh  = (u16*)(base + 12582912);     //  8 MB
    u16*   DTh  = (u16*)(base + 20971520);     //  8 MB
    u16*   QKVT = (u16*)(base + 29360128);     //  3 MB
    u16*   Xh   = (u16*)(base + 32505856);     //  8 MB
    u16*   Qbh  = (u16*)(base + 40894464);     //  8 MB
    u16*   Qbl  = (u16*)(base + 49283072);     //  8 MB
    u16*   Kbh  = (u16*)(base + 57671680);     //  2 MB
    u16*   Kbl  = (u16*)(base + 59768832);     //  2 MB
    u16*   Vth  = (u16*)(base + 61865984);     //  2 MB
    u16*   Vtl  = (u16*)(base + 63963136);     //  2 MB
    u16*   AOh  = (u16*)(base + 66060288);     //  8 MB
    u16*   AOl  = (u16*)(base + 74448896);     //  8 MB
    u16*   FFh  = (u16*)(base + 82837504);     // 32 MB (end 116,391,936)

    // aliases (lifetime-checked):
    float* H2 = (float*)Qbh;   // 16 MB over Qbh+Qbl (Q dead post-attn)
    u16*   Yh = Kbh;           //  8 MB over Kbh..Vtl (K/V dead post-attn)
    u16*   Yl = AOh;           //  8 MB over AOh (AO dead post-o-proj)

    // 0. all weight prep + fused rmsnorm(ln1) in one launch
    wprep_all_kernel<<<14848 + Mrows, 256, 0, stream>>>(
        q_w, k_w, v_w, o_w, gate_w, up_w, down_w, hidden, ln1,
        QKVT, OTh, OTl, GTh, UTh, DTh, Xh);

    // 1. fused qkv projection + qknorm + rope + split + V-transpose
    qkv_fused_kernel<<<dim3(12, 32), 256, 0, stream>>>(
        Xh, QKVT, qn, kn, sinp, cosp, Qbh, Qbl, Kbh, Kbl, Vth, Vtl);

    // 2. MFMA flash attention — r16 paired-window blocks, heavy-first (512)
    attn_mfma_kernel<<<Bsz * Gg * (Tseq / 32), 512, 0, stream>>>(
        Qbh, Qbl, Kbh, Kbl, Vth, Vtl, AOh, AOl);

    // 3. hidden2 = hidden + attn @ o_w  (split x split) — BN=128, r19 1-barrier
    mfma_gemm_pipe<32, 128, 1, 1, 1><<<dim3(8, 32), 256, 0, stream>>>(
        AOh, AOl, OTh, OTl, hidden, H2, Mrows, Dmod);

    // 4. y = rmsnorm(hidden2, ln2) -> bf16 hi/lo
    rmsnorm_split_kernel<1><<<Mrows, 256, 0, stream>>>(H2, ln2, Yh, Yl);

    // 5. ff = silu(y@gate_w) * (y@up_w) -> FF bf16 — r19 1-barrier/K-step
    gateup8_kernel<<<512, 512, 0, stream>>>(Yh, Yl, GTh, UTh, FFh);

    // 6. out = hidden2 + ff @ down_w — BN=128, r19 1-barrier
    mfma_gemm_pipe<128, 128, 0, 0, 1><<<dim3(8, 32), 256, 0, stream>>>(
        FFh, nullptr, DTh, nullptr, H2, out, Mrows, Dmod);
}